// Round 4
// baseline (432.372 us; speedup 1.0000x reference)
//
#include <hip/hip_runtime.h>
#include <hip/hip_bf16.h>

// ---------------------------------------------------------------------------
// 2-layer GATConv (heads=1). N=50000, E=800000, Cin=128, Ch=256, Co=128, Ed=8.
// 8-dispatch pipeline:
//   memset | prep (W-split + we_vec) | FAT [hist+rank+aEe ∥ gemm1] |
//   fused-scan | fill (atomic-free) | agg1 | gemm2 | agg2
// R4: the 800k-atomic histogram (throughput-bound at the L2/L3 atomic point,
// ~65 us with the machine idle) is overlapped with the independent gemm1
// MFMA work in one fat kernel. Hist blocks lead the grid to start the atomic
// stream; gemm blocks fill in behind. we_vec computed once in prep, not per
// hist block.
// ---------------------------------------------------------------------------

#define NEG_SLOPE 0.2f

typedef unsigned short u16;
typedef short short8 __attribute__((ext_vector_type(8)));
typedef float v4f __attribute__((ext_vector_type(4)));
typedef u16 u16x4 __attribute__((ext_vector_type(4)));
typedef u16 u16x8 __attribute__((ext_vector_type(8)));

__device__ __forceinline__ u16 f2bf(float f) {
    unsigned u = __float_as_uint(f);
    return (u16)((u + 0x7fffu + ((u >> 16) & 1u)) >> 16);
}
__device__ __forceinline__ float bf2f(u16 h) {
    return __uint_as_float(((unsigned)h) << 16);
}
__device__ __forceinline__ float bf_lo(int v) { return __uint_as_float(((unsigned)v) << 16); }
__device__ __forceinline__ float bf_hi(int v) { return __uint_as_float(((unsigned)v) & 0xffff0000u); }
__device__ __forceinline__ float lrelu(float x) {
    return x >= 0.f ? x : NEG_SLOPE * x;
}
__device__ __forceinline__ int ld_acq(int* p) {
    return __hip_atomic_load(p, __ATOMIC_ACQUIRE, __HIP_MEMORY_SCOPE_AGENT);
}
__device__ __forceinline__ void st_rel(int* p, int v) {
    __hip_atomic_store(p, v, __ATOMIC_RELEASE, __HIP_MEMORY_SCOPE_AGENT);
}

// ---- prep: [blocks 0..256): W1^T / W2^T bf16 hi/lo splits
//            [block 256]: we_vec1/2 = We^T @ ae (computed once, published) ---
__global__ __launch_bounds__(256) void prep_kernel(
        const float* __restrict__ W1, u16* __restrict__ w1thi, u16* __restrict__ w1tlo,
        const float* __restrict__ W2, u16* __restrict__ w2thi, u16* __restrict__ w2tlo,
        const float* __restrict__ We1, const float* __restrict__ ae1v,
        const float* __restrict__ We2, const float* __restrict__ ae2v,
        float* __restrict__ we_vec1g, float* __restrict__ we_vec2g) {
    int tid = threadIdx.x;
    if (blockIdx.x < 256) {
        int t = blockIdx.x * 256 + tid;
        if (t < 128 * 256) {               // W1 [Cin=128][Ch=256]
            int k = t >> 8, m = t & 255;
            float v = W1[t];
            u16 h = f2bf(v);
            w1thi[(size_t)m * 128 + k] = h;
            w1tlo[(size_t)m * 128 + k] = f2bf(v - bf2f(h));
        } else {                           // W2 [Ch=256][Co=128]
            t -= 128 * 256;
            int k = t >> 7, m = t & 127;
            float v = W2[t];
            u16 h = f2bf(v);
            w2thi[(size_t)m * 256 + k] = h;
            w2tlo[(size_t)m * 256 + k] = f2bf(v - bf2f(h));
        }
        return;
    }
    // ---- we_vec: wv[j] = sum_k We1[j][k]*ae1v[k]; wv[8+j] for We2 ----
    __shared__ float wv[16];
    if (tid < 16) wv[tid] = 0.f;
    __syncthreads();
    {
        float a1 = ae1v[tid];              // Ch == 256 == blockDim
        int lane = tid & 63;
#pragma unroll
        for (int j = 0; j < 8; ++j) {
            float v = We1[j * 256 + tid] * a1;
#pragma unroll
            for (int o = 32; o; o >>= 1) v += __shfl_down(v, o);
            if (lane == 0) atomicAdd(&wv[j], v);
        }
        if (tid < 128) {
            float a2 = ae2v[tid];          // Co == 128
#pragma unroll
            for (int j = 0; j < 8; ++j) {
                float v = We2[j * 128 + tid] * a2;
#pragma unroll
                for (int o = 32; o; o >>= 1) v += __shfl_down(v, o);
                if (lane == 0) atomicAdd(&wv[8 + j], v);
            }
        }
    }
    __syncthreads();
    if (tid < 8)  we_vec1g[tid] = wv[tid];
    else if (tid < 16) we_vec2g[tid - 8] = wv[tid];
}

// ---- FAT: [blocks 0..Fb): edge hist (fetch-add -> rank) + ea sums + a_e
//           [blocks Fb..Fb+Gg): gemm1 (A = fp32 x, converted while staging)
// Hist blocks lead so the atomic stream starts immediately; gemm MFMA work
// executes underneath the atomic drain.
#define BK 32
#define LDA 40   // 32 + 8 pad (u16)
__global__ __launch_bounds__(256) void fat1_kernel(
        // hist args
        const float* __restrict__ ea, const int* __restrict__ dst,
        float* __restrict__ mean_acc, int* __restrict__ deg,
        int* __restrict__ rank, float2* __restrict__ aEe, int E,
        const float* __restrict__ we_vec1g, const float* __restrict__ we_vec2g,
        int Fb,
        // gemm args
        const float* __restrict__ A32,
        const u16* __restrict__ Bh_g, const u16* __restrict__ Bl_g,
        u16* __restrict__ Cb, int Nrows, int K, int M,
        const float* __restrict__ av, const float* __restrict__ bv,
        float* __restrict__ as_out, float* __restrict__ ad_out, int gx) {
    __shared__ u16 Ah[128 * LDA], Bh[128 * LDA], Bl[128 * LDA];
    int tid = threadIdx.x;
    if ((int)blockIdx.x < Fb) {
        // ---- hist branch ----
        __shared__ float red[8];
        __shared__ float wv[16];
        if (tid < 16) { wv[tid] = (tid < 8) ? we_vec1g[tid] : we_vec2g[tid - 8];
                        if (tid < 8) red[tid] = 0.f; }
        __syncthreads();
        int e = (int)blockIdx.x * 256 + tid;
        float s[8] = {0.f};
        if (e < E) {
            const float4 v0 = *(const float4*)&ea[(size_t)e * 8];
            const float4 v1 = *(const float4*)&ea[(size_t)e * 8 + 4];
            int d = dst[e];
            s[0] = v0.x; s[1] = v0.y; s[2] = v0.z; s[3] = v0.w;
            s[4] = v1.x; s[5] = v1.y; s[6] = v1.z; s[7] = v1.w;
            float s1 = v0.x * wv[0] + v0.y * wv[1] + v0.z * wv[2] + v0.w * wv[3]
                     + v1.x * wv[4] + v1.y * wv[5] + v1.z * wv[6] + v1.w * wv[7];
            float s2 = v0.x * wv[8] + v0.y * wv[9] + v0.z * wv[10] + v0.w * wv[11]
                     + v1.x * wv[12] + v1.y * wv[13] + v1.z * wv[14] + v1.w * wv[15];
            aEe[e] = make_float2(s1, s2);
            rank[e] = atomicAdd(&deg[d], 1);   // returning fetch-add: arrival rank
        }
        int lane = tid & 63;
#pragma unroll
        for (int j = 0; j < 8; ++j) {
#pragma unroll
            for (int o = 32; o; o >>= 1) s[j] += __shfl_down(s[j], o);
            if (lane == 0) atomicAdd(&red[j], s[j]);
        }
        __syncthreads();
        if (tid < 8) atomicAdd(&mean_acc[tid], red[tid]);
        return;
    }
    // ---- gemm1 branch ----
    int gb = (int)blockIdx.x - Fb;
    int lane = tid & 63;
    int wvx = tid >> 6;
    int wm = wvx >> 1, wn = wvx & 1;
    int l15 = lane & 15, quad = lane >> 4;
    int rb = (gb / gx) * 128;
    int cb = (gb % gx) * 128;

    v4f acc[4][4];
#pragma unroll
    for (int mi = 0; mi < 4; ++mi)
#pragma unroll
        for (int ni = 0; ni < 4; ++ni) acc[mi][ni] = (v4f){0.f, 0.f, 0.f, 0.f};

    int sr = tid >> 1;
    int sc = (tid & 1) * 16;

    for (int kc = 0; kc < K; kc += BK) {
        int gr = rb + sr;
        u16x8 a0 = {0,0,0,0,0,0,0,0}, a1 = {0,0,0,0,0,0,0,0};
        if (gr < Nrows) {
            const float* pa = A32 + (size_t)gr * K + kc + sc;
            float4 f0 = *(const float4*)pa;
            float4 f1 = *(const float4*)(pa + 4);
            float4 f2 = *(const float4*)(pa + 8);
            float4 f3 = *(const float4*)(pa + 12);
            a0 = (u16x8){f2bf(f0.x), f2bf(f0.y), f2bf(f0.z), f2bf(f0.w),
                         f2bf(f1.x), f2bf(f1.y), f2bf(f1.z), f2bf(f1.w)};
            a1 = (u16x8){f2bf(f2.x), f2bf(f2.y), f2bf(f2.z), f2bf(f2.w),
                         f2bf(f3.x), f2bf(f3.y), f2bf(f3.z), f2bf(f3.w)};
        }
        size_t bb = (size_t)(cb + sr) * K + kc + sc;
        u16x8 b0 = *(const u16x8*)(Bh_g + bb);
        u16x8 b1 = *(const u16x8*)(Bh_g + bb + 8);
        u16x8 b2 = *(const u16x8*)(Bl_g + bb);
        u16x8 b3 = *(const u16x8*)(Bl_g + bb + 8);
        *(u16x8*)&Ah[sr * LDA + sc] = a0;
        *(u16x8*)&Ah[sr * LDA + sc + 8] = a1;
        *(u16x8*)&Bh[sr * LDA + sc] = b0;
        *(u16x8*)&Bh[sr * LDA + sc + 8] = b1;
        *(u16x8*)&Bl[sr * LDA + sc] = b2;
        *(u16x8*)&Bl[sr * LDA + sc + 8] = b3;
        __syncthreads();
        short8 ah[4], bh[4], bl[4];
#pragma unroll
        for (int mi = 0; mi < 4; ++mi)
            ah[mi] = *(const short8*)&Ah[(wm * 64 + mi * 16 + l15) * LDA + quad * 8];
#pragma unroll
        for (int ni = 0; ni < 4; ++ni) {
            int r = (wn * 64 + ni * 16 + l15) * LDA + quad * 8;
            bh[ni] = *(const short8*)&Bh[r];
            bl[ni] = *(const short8*)&Bl[r];
        }
#pragma unroll
        for (int mi = 0; mi < 4; ++mi)
#pragma unroll
            for (int ni = 0; ni < 4; ++ni) {
                acc[mi][ni] = __builtin_amdgcn_mfma_f32_16x16x32_bf16(ah[mi], bh[ni], acc[mi][ni], 0, 0, 0);
                acc[mi][ni] = __builtin_amdgcn_mfma_f32_16x16x32_bf16(ah[mi], bl[ni], acc[mi][ni], 0, 0, 0);
            }
        __syncthreads();
    }
#pragma unroll
    for (int mi = 0; mi < 4; ++mi)
#pragma unroll
        for (int ni = 0; ni < 4; ++ni)
#pragma unroll
            for (int reg = 0; reg < 4; ++reg) {
                int row = rb + wm * 64 + mi * 16 + quad * 4 + reg;
                if (row < Nrows)
                    Cb[(size_t)row * M + cb + wn * 64 + ni * 16 + l15] = f2bf(acc[mi][ni][reg]);
            }
    float sd[4][4] = {}, dd[4][4] = {};
#pragma unroll
    for (int ni = 0; ni < 4; ++ni) {
        int col = cb + wn * 64 + ni * 16 + l15;
        float a = av[col], b = bv[col];
#pragma unroll
        for (int mi = 0; mi < 4; ++mi)
#pragma unroll
            for (int reg = 0; reg < 4; ++reg) {
                sd[mi][reg] += acc[mi][ni][reg] * a;
                dd[mi][reg] += acc[mi][ni][reg] * b;
            }
    }
#pragma unroll
    for (int off = 1; off < 16; off <<= 1)
#pragma unroll
        for (int mi = 0; mi < 4; ++mi)
#pragma unroll
            for (int reg = 0; reg < 4; ++reg) {
                sd[mi][reg] += __shfl_xor(sd[mi][reg], off);
                dd[mi][reg] += __shfl_xor(dd[mi][reg], off);
            }
    if (l15 == 0)
#pragma unroll
        for (int mi = 0; mi < 4; ++mi) {
            int row0 = rb + wm * 64 + mi * 16 + quad * 4;
#pragma unroll
            for (int reg = 0; reg < 4; ++reg)
                if (row0 + reg < Nrows) {
                    atomicAdd(as_out + row0 + reg, sd[mi][reg]);
                    atomicAdd(ad_out + row0 + reg, dd[mi][reg]);
                }
        }
}

// ---- fused single-kernel exclusive scan (196 blocks, all co-resident) ------
__global__ __launch_bounds__(256) void scan_fused_kernel(
        const int* __restrict__ deg, int* __restrict__ row_start,
        int* __restrict__ partials, int* __restrict__ pprefix,
        int* __restrict__ gcount, int* __restrict__ gflag, int N, int n,
        const float* __restrict__ mean_acc, float Einv,
        const float* __restrict__ we_vec1, const float* __restrict__ we_vec2,
        float* __restrict__ ae_loop) {
    __shared__ int s[256];
    __shared__ int amLast, bprefix;
    int t = threadIdx.x, bid = blockIdx.x;
    int i = bid * 256 + t;
    int v = (i < N) ? deg[i] : 0;
    s[t] = v; __syncthreads();
    for (int off = 1; off < 256; off <<= 1) {
        int u = (t >= off) ? s[t - off] : 0;
        __syncthreads();
        s[t] += u;
        __syncthreads();
    }
    int incl = s[t];
    int total = s[255];
    if (t == 0) {
        partials[bid] = total;
        __threadfence();
        int c = __hip_atomic_fetch_add(gcount, 1, __ATOMIC_ACQ_REL, __HIP_MEMORY_SCOPE_AGENT);
        amLast = (c == (int)gridDim.x - 1);
    }
    __syncthreads();
    if (amLast) {
        int G = gridDim.x;
        int pv = (t < G) ? ld_acq(&partials[t]) : 0;
        __syncthreads();           // s[] reuse
        s[t] = pv; __syncthreads();
        for (int off = 1; off < 256; off <<= 1) {
            int u = (t >= off) ? s[t - off] : 0;
            __syncthreads();
            s[t] += u;
            __syncthreads();
        }
        if (t < G) pprefix[t] = s[t] - pv;
        if (t == 0) {
            float s1 = 0.f, s2 = 0.f;
#pragma unroll
            for (int j = 0; j < 8; ++j) {
                float m = mean_acc[j] * Einv;
                s1 += m * we_vec1[j];
                s2 += m * we_vec2[j];
            }
            ae_loop[0] = s1; ae_loop[1] = s2;
        }
        __threadfence();
        __syncthreads();
        if (t == 0) st_rel(gflag, 1);
    }
    if (t == 0) {
        while (ld_acq(gflag) == 0) __builtin_amdgcn_s_sleep(2);
        bprefix = ld_acq(&pprefix[bid]);
    }
    __syncthreads();
    int ex = bprefix + incl - v;
    if (i < n) row_start[i] = ex;
}

// ---- CSR fill: atomic-free (slot = row_start[dst] + rank), max TLP ---------
__global__ __launch_bounds__(256) void fill_kernel(
        const int* __restrict__ src, const int* __restrict__ dst,
        const float2* __restrict__ aEe, const int* __restrict__ row_start,
        const int* __restrict__ rank,
        float4* __restrict__ epack, int E) {
    int e = blockIdx.x * 256 + threadIdx.x;
    if (e >= E) return;
    int d = dst[e];
    int idx = row_start[d] + rank[e];
    float2 a = aEe[e];
    epack[idx] = make_float4(__int_as_float(src[e]), a.x, a.y, 0.f);
}

// ---- gemm2: A already bf16 --------------------------------------------------
__global__ __launch_bounds__(256) void gemm_mfma_kernel(
        const u16* __restrict__ A_g,
        const u16* __restrict__ Bh_g, const u16* __restrict__ Bl_g,
        u16* __restrict__ Cb, int Nrows, int K, int M,
        const float* __restrict__ av, const float* __restrict__ bv,
        float* __restrict__ as_out, float* __restrict__ ad_out) {
    __shared__ u16 Ah[128 * LDA], Bh[128 * LDA], Bl[128 * LDA];
    int tid = threadIdx.x;
    int lane = tid & 63;
    int wv = tid >> 6;
    int wm = wv >> 1, wn = wv & 1;
    int l15 = lane & 15, quad = lane >> 4;
    int rb = blockIdx.y * 128;
    int cb = blockIdx.x * 128;

    v4f acc[4][4];
#pragma unroll
    for (int mi = 0; mi < 4; ++mi)
#pragma unroll
        for (int ni = 0; ni < 4; ++ni) acc[mi][ni] = (v4f){0.f, 0.f, 0.f, 0.f};

    int sr = tid >> 1;
    int sc = (tid & 1) * 16;

    for (int kc = 0; kc < K; kc += BK) {
        int gr = rb + sr;
        u16x8 a0 = {0,0,0,0,0,0,0,0}, a1 = {0,0,0,0,0,0,0,0};
        if (gr < Nrows) {
            size_t ba = (size_t)gr * K + kc + sc;
            a0 = *(const u16x8*)(A_g + ba);
            a1 = *(const u16x8*)(A_g + ba + 8);
        }
        size_t bb = (size_t)(cb + sr) * K + kc + sc;
        u16x8 b0 = *(const u16x8*)(Bh_g + bb);
        u16x8 b1 = *(const u16x8*)(Bh_g + bb + 8);
        u16x8 b2 = *(const u16x8*)(Bl_g + bb);
        u16x8 b3 = *(const u16x8*)(Bl_g + bb + 8);
        *(u16x8*)&Ah[sr * LDA + sc] = a0;
        *(u16x8*)&Ah[sr * LDA + sc + 8] = a1;
        *(u16x8*)&Bh[sr * LDA + sc] = b0;
        *(u16x8*)&Bh[sr * LDA + sc + 8] = b1;
        *(u16x8*)&Bl[sr * LDA + sc] = b2;
        *(u16x8*)&Bl[sr * LDA + sc + 8] = b3;
        __syncthreads();
        short8 ah[4], bh[4], bl[4];
#pragma unroll
        for (int mi = 0; mi < 4; ++mi)
            ah[mi] = *(const short8*)&Ah[(wm * 64 + mi * 16 + l15) * LDA + quad * 8];
#pragma unroll
        for (int ni = 0; ni < 4; ++ni) {
            int r = (wn * 64 + ni * 16 + l15) * LDA + quad * 8;
            bh[ni] = *(const short8*)&Bh[r];
            bl[ni] = *(const short8*)&Bl[r];
        }
#pragma unroll
        for (int mi = 0; mi < 4; ++mi)
#pragma unroll
            for (int ni = 0; ni < 4; ++ni) {
                acc[mi][ni] = __builtin_amdgcn_mfma_f32_16x16x32_bf16(ah[mi], bh[ni], acc[mi][ni], 0, 0, 0);
                acc[mi][ni] = __builtin_amdgcn_mfma_f32_16x16x32_bf16(ah[mi], bl[ni], acc[mi][ni], 0, 0, 0);
            }
        __syncthreads();
    }
#pragma unroll
    for (int mi = 0; mi < 4; ++mi)
#pragma unroll
        for (int ni = 0; ni < 4; ++ni)
#pragma unroll
            for (int reg = 0; reg < 4; ++reg) {
                int row = rb + wm * 64 + mi * 16 + quad * 4 + reg;
                if (row < Nrows)
                    Cb[(size_t)row * M + cb + wn * 64 + ni * 16 + l15] = f2bf(acc[mi][ni][reg]);
            }
    float sd[4][4] = {}, dd[4][4] = {};
#pragma unroll
    for (int ni = 0; ni < 4; ++ni) {
        int col = cb + wn * 64 + ni * 16 + l15;
        float a = av[col], b = bv[col];
#pragma unroll
        for (int mi = 0; mi < 4; ++mi)
#pragma unroll
            for (int reg = 0; reg < 4; ++reg) {
                sd[mi][reg] += acc[mi][ni][reg] * a;
                dd[mi][reg] += acc[mi][ni][reg] * b;
            }
    }
#pragma unroll
    for (int off = 1; off < 16; off <<= 1)
#pragma unroll
        for (int mi = 0; mi < 4; ++mi)
#pragma unroll
            for (int reg = 0; reg < 4; ++reg) {
                sd[mi][reg] += __shfl_xor(sd[mi][reg], off);
                dd[mi][reg] += __shfl_xor(dd[mi][reg], off);
            }
    if (l15 == 0)
#pragma unroll
        for (int mi = 0; mi < 4; ++mi) {
            int row0 = rb + wm * 64 + mi * 16 + quad * 4;
#pragma unroll
            for (int reg = 0; reg < 4; ++reg)
                if (row0 + reg < Nrows) {
                    atomicAdd(as_out + row0 + reg, sd[mi][reg]);
                    atomicAdd(ad_out + row0 + reg, dd[mi][reg]);
                }
        }
}

// ---- single-pass FLASH softmax-aggregation, L1 (C=256), wave per node ------
__global__ __launch_bounds__(256) void agg1_kernel(const int* __restrict__ row_start,
                                                   const float4* __restrict__ epack,
                                                   const float* __restrict__ asv,
                                                   const float* __restrict__ adv,
                                                   const float* __restrict__ ae_loop,
                                                   const u16* __restrict__ Hb,
                                                   u16* __restrict__ ohi,
                                                   const float* __restrict__ bias, int N) {
    __shared__ float2 xch[4][64];
    int lane = threadIdx.x & 63;
    int wvi = threadIdx.x >> 6;
    int node = blockIdx.x * 4 + wvi;
    if (node >= N) return;
    int st = row_start[node], en = row_start[node + 1];
    float ad = adv[node];
    float aloop = lrelu(asv[node] + ad + ae_loop[0]);
    float m = aloop, sum = 1.f;
    float acc0, acc1, acc2, acc3;
    {
        int2 hv = *(const int2*)(Hb + (size_t)node * 256 + lane * 4);
        acc0 = bf_lo(hv.x); acc1 = bf_hi(hv.x);
        acc2 = bf_lo(hv.y); acc3 = bf_hi(hv.y);
    }
    for (int base = st; base < en; base += 64) {
        int i = base + lane;
        float al = -3.0e38f; int sreg = 0;
        if (i < en) {
            float4 ep = epack[i];
            sreg = __float_as_int(ep.x);
            al = lrelu(asv[sreg] + ad + ep.y);
        }
        float cm = al;
#pragma unroll
        for (int o = 1; o < 64; o <<= 1) cm = fmaxf(cm, __shfl_xor(cm, o));
        if (cm > m) {
            float sc = __expf(m - cm);
            acc0 *= sc; acc1 *= sc; acc2 *= sc; acc3 *= sc;
            sum *= sc; m = cm;
        }
        float w = (i < en) ? __expf(al - m) : 0.f;
        float wsum = w;
#pragma unroll
        for (int o = 1; o < 64; o <<= 1) wsum += __shfl_xor(wsum, o);
        sum += wsum;
        xch[wvi][lane] = make_float2(w, __int_as_float(sreg));
        int cnt = min(64, en - base);
        int j = 0;
        for (; j + 8 <= cnt; j += 8) {
            float2 e[8]; int2 h[8];
#pragma unroll
            for (int q = 0; q < 8; ++q) e[q] = xch[wvi][j + q];
#pragma unroll
            for (int q = 0; q < 8; ++q)
                h[q] = *(const int2*)(Hb + (size_t)__float_as_int(e[q].y) * 256 + lane * 4);
#pragma unroll
            for (int q = 0; q < 8; ++q) {
                acc0 += e[q].x * bf_lo(h[q].x); acc1 += e[q].x * bf_hi(h[q].x);
                acc2 += e[q].x * bf_lo(h[q].y); acc3 += e[q].x * bf_hi(h[q].y);
            }
        }
        for (; j + 4 <= cnt; j += 4) {
            float2 e0 = xch[wvi][j], e1 = xch[wvi][j + 1];
            float2 e2 = xch[wvi][j + 2], e3 = xch[wvi][j + 3];
            int2 h0 = *(const int2*)(Hb + (size_t)__float_as_int(e0.y) * 256 + lane * 4);
            int2 h1 = *(const int2*)(Hb + (size_t)__float_as_int(e1.y) * 256 + lane * 4);
            int2 h2 = *(const int2*)(Hb + (size_t)__float_as_int(e2.y) * 256 + lane * 4);
            int2 h3 = *(const int2*)(Hb + (size_t)__float_as_int(e3.y) * 256 + lane * 4);
            acc0 += e0.x * bf_lo(h0.x) + e1.x * bf_lo(h1.x) + e2.x * bf_lo(h2.x) + e3.x * bf_lo(h3.x);
            acc1 += e0.x * bf_hi(h0.x) + e1.x * bf_hi(h1.x) + e2.x * bf_hi(h2.x) + e3.x * bf_hi(h3.x);
            acc2 += e0.x * bf_lo(h0.y) + e1.x * bf_lo(h1.y) + e2.x * bf_lo(h2.y) + e3.x * bf_lo(h3.y);
            acc3 += e0.x * bf_hi(h0.y) + e1.x * bf_hi(h1.y) + e2.x * bf_hi(h2.y) + e3.x * bf_hi(h3.y);
        }
        for (; j < cnt; ++j) {
            float2 e0 = xch[wvi][j];
            int2 h0 = *(const int2*)(Hb + (size_t)__float_as_int(e0.y) * 256 + lane * 4);
            acc0 += e0.x * bf_lo(h0.x); acc1 += e0.x * bf_hi(h0.x);
            acc2 += e0.x * bf_lo(h0.y); acc3 += e0.x * bf_hi(h0.y);
        }
    }
    float inv = 1.f / sum;
    const float4 bvv = *(const float4*)(bias + lane * 4);
    float t0 = acc0 * inv + bvv.x, t1 = acc1 * inv + bvv.y;
    float t2 = acc2 * inv + bvv.z, t3 = acc3 * inv + bvv.w;
    t0 = t0 > 0.f ? t0 : 0.f; t1 = t1 > 0.f ? t1 : 0.f;
    t2 = t2 > 0.f ? t2 : 0.f; t3 = t3 > 0.f ? t3 : 0.f;
    u16x4 h;
    h.x = f2bf(t0); h.y = f2bf(t1); h.z = f2bf(t2); h.w = f2bf(t3);
    *(u16x4*)(ohi + (size_t)node * 256 + lane * 4) = h;
}

// ---- single-pass FLASH softmax-aggregation, L2 (C=128) ---------------------
__global__ __launch_bounds__(256) void agg2_kernel(const int* __restrict__ row_start,
                                                   const float4* __restrict__ epack,
                                                   const float* __restrict__ asv,
                                                   const float* __restrict__ adv,
                                                   const float* __restrict__ ae_loop,
                                                   const u16* __restrict__ Hb,
                                                   float* __restrict__ out,
                                                   const float* __restrict__ bias, int N) {
    __shared__ float2 xch[4][64];
    int lane = threadIdx.x & 63;
    int wvi = threadIdx.x >> 6;
    int node = blockIdx.x * 4 + wvi;
    if (node >= N) return;
    int st = row_start[node], en = row_start[node + 1];
    float ad = adv[node];
    float aloop = lrelu(asv[node] + ad + ae_loop[1]);
    float m = aloop, sum = 1.f;
    float acc0, acc1;
    {
        int hv = *(const int*)(Hb + (size_t)node * 128 + lane * 2);
        acc0 = bf_lo(hv); acc1 = bf_hi(hv);
    }
    for (int base = st; base < en; base += 64) {
        int i = base + lane;
        float al = -3.0e38f; int sreg = 0;
        if (i < en) {
            float4 ep = epack[i];
            sreg = __float_as_int(ep.x);
            al = lrelu(asv[sreg] + ad + ep.z);
        }
        float cm = al;
#pragma unroll
        for (int o = 1; o < 64; o <<= 1) cm = fmaxf(cm, __shfl_xor(cm, o));
        if (cm > m) {
            float sc = __expf(m - cm);
            acc0 *= sc; acc1 *= sc;
            sum *= sc; m = cm;
        }
        float w = (i < en) ? __expf(al - m) : 0.f;
        float wsum = w;
#pragma unroll
        for (int o = 1; o < 64; o <<= 1) wsum += __shfl_xor(wsum, o);
        sum += wsum;
        xch[wvi][lane] = make_float2(w, __int_as_float(sreg));
        int cnt = min(64, en - base);
        int j = 0;
        for (; j + 8 <= cnt; j += 8) {
            float2 e[8]; int h[8];
#pragma unroll
            for (int q = 0; q < 8; ++q) e[q] = xch[wvi][j + q];
#pragma unroll
            for (int q = 0; q < 8; ++q)
                h[q] = *(const int*)(Hb + (size_t)__float_as_int(e[q].y) * 128 + lane * 2);
#pragma unroll
            for (int q = 0; q < 8; ++q) {
                acc0 += e[q].x * bf_lo(h[q]); acc1 += e[q].x * bf_hi(h[q]);
            }
        }
        for (; j + 4 <= cnt; j += 4) {
            float2 e0 = xch[wvi][j], e1 = xch[wvi][j + 1];
            float2 e2 = xch[wvi][j + 2], e3 = xch[wvi][j + 3];
            int h0 = *(const int*)(Hb + (size_t)__float_as_int(e0.y) * 128 + lane * 2);
            int h1 = *(const int*)(Hb + (size_t)__float_as_int(e1.y) * 128 + lane * 2);
            int h2 = *(const int*)(Hb + (size_t)__float_as_int(e2.y) * 128 + lane * 2);
            int h3 = *(const int*)(Hb + (size_t)__float_as_int(e3.y) * 128 + lane * 2);
            acc0 += e0.x * bf_lo(h0) + e1.x * bf_lo(h1) + e2.x * bf_lo(h2) + e3.x * bf_lo(h3);
            acc1 += e0.x * bf_hi(h0) + e1.x * bf_hi(h1) + e2.x * bf_hi(h2) + e3.x * bf_hi(h3);
        }
        for (; j < cnt; ++j) {
            float2 e0 = xch[wvi][j];
            int h0 = *(const int*)(Hb + (size_t)__float_as_int(e0.y) * 128 + lane * 2);
            acc0 += e0.x * bf_lo(h0); acc1 += e0.x * bf_hi(h0);
        }
    }
    float inv = 1.f / sum;
    size_t o = (size_t)node * 128 + lane * 2;
    out[o]     = acc0 * inv + bias[lane * 2];
    out[o + 1] = acc1 * inv + bias[lane * 2 + 1];
}

extern "C" void kernel_launch(void* const* d_in, const int* in_sizes, int n_in,
                              void* d_out, int out_size, void* d_ws, size_t ws_size,
                              hipStream_t stream) {
    const int Cin = 128, Ch = 256, Co = 128;
    const int N = in_sizes[0] / Cin;        // 50000
    const int E = in_sizes[1] / 2;          // 800000

    const float* x   = (const float*)d_in[0];
    const int*   src = (const int*)d_in[1];
    const int*   dst = src + E;
    const float* ea  = (const float*)d_in[2];
    const float* W1  = (const float*)d_in[3];
    const float* We1 = (const float*)d_in[4];
    const float* as1 = (const float*)d_in[5];
    const float* ad1 = (const float*)d_in[6];
    const float* ae1 = (const float*)d_in[7];
    const float* b1  = (const float*)d_in[8];
    const float* W2  = (const float*)d_in[9];
    const float* We2 = (const float*)d_in[10];
    const float* as2 = (const float*)d_in[11];
    const float* ad2 = (const float*)d_in[12];
    const float* ae2 = (const float*)d_in[13];
    const float* b2  = (const float*)d_in[14];
    float* out = (float*)d_out;

    // workspace layout (4-byte units)
    float* ws = (float*)d_ws;
    size_t off = 0;
    u16* h1b = (u16*)(ws + off); off += (size_t)N * Ch / 2;   // bf16 h (reused as h2b)
    u16* g1b = (u16*)(ws + off); off += (size_t)N * Ch / 2;   // agg1 output (gemm2 A)
    float4* epack = (float4*)(ws + off); off += (size_t)E * 4;  // packed CSR edges
    float2* aEe   = (float2*)(ws + off); off += (size_t)E * 2;  // edge-order a_e
    int* rank     = (int*)(ws + off); off += (size_t)E;         // per-edge rank
    int* row_start = (int*)(ws + off); off += (size_t)N + 1;
    int* partials  = (int*)(ws + off); off += 256;
    int* pprefix   = (int*)(ws + off); off += 256;
    u16* w1thi = (u16*)(ws + off); off += (size_t)Cin * Ch / 2;
    u16* w1tlo = (u16*)(ws + off); off += (size_t)Cin * Ch / 2;
    u16* w2thi = (u16*)(ws + off); off += (size_t)Ch * Co / 2;
    u16* w2tlo = (u16*)(ws + off); off += (size_t)Ch * Co / 2;
    // contiguous zero-region: deg | asv1 adv1 asv2 adv2 | misc | sync
    int*   deg  = (int*)(ws + off); off += (size_t)N + 1;
    float* asv1 = ws + off; off += (size_t)N;
    float* adv1 = ws + off; off += (size_t)N;
    float* asv2 = ws + off; off += (size_t)N;
    float* adv2 = ws + off; off += (size_t)N;
    float* misc = ws + off; off += 32;
    float* mean_acc = misc;
    float* we_vec1  = misc + 8;
    float* we_vec2  = misc + 16;
    float* ae_loop  = misc + 24;
    int* gcount = (int*)(ws + off); off += 1;
    int* gflag  = (int*)(ws + off); off += 1;

    const int n1 = N + 1;
    const int nscan = (n1 + 255) / 256;   // 196 blocks <= 256 CUs (co-resident)

    // one memset zeroes deg + 4 dot-buffers + misc + sync flags
    hipMemsetAsync(deg, 0, ((size_t)5 * N + 35) * sizeof(float), stream);

    // ---- prep: W splits (256 blocks) + we_vec (1 block) --------------------
    prep_kernel<<<257, 256, 0, stream>>>(
        W1, w1thi, w1tlo, W2, w2thi, w2tlo,
        We1, ae1, We2, ae2, we_vec1, we_vec2);

    // ---- FAT: hist+rank+aEe (3125 blocks, first) || gemm1 (782 blocks) -----
    {
        int Fb = (E + 255) / 256;                // 3125
        int gx = Ch / 128;                       // 2
        int Gg = gx * ((N + 127) / 128);         // 782
        fat1_kernel<<<Fb + Gg, 256, 0, stream>>>(
            ea, dst, mean_acc, deg, rank, aEe, E, we_vec1, we_vec2, Fb,
            x, w1thi, w1tlo, h1b, N, Cin, Ch, as1, ad1, asv1, adv1, gx);
    }

    // ---- fused scan (+ae_loop) ---------------------------------------------
    scan_fused_kernel<<<nscan, 256, 0, stream>>>(
        deg, row_start, partials, pprefix, gcount, gflag, N, n1,
        mean_acc, 1.0f / (float)E, we_vec1, we_vec2, ae_loop);

    // ---- CSR fill: atomic-free ---------------------------------------------
    fill_kernel<<<(E + 255) / 256, 256, 0, stream>>>(src, dst, aEe, row_start,
                                                     rank, epack, E);

    agg1_kernel<<<(N + 3) / 4, 256, 0, stream>>>(row_start, epack, asv1, adv1, ae_loop,
                                                 h1b, g1b, b1, N);

    // ---- layer 2 ----------------------------------------------------------
    u16* h2b = h1b; // reuse (agg1 consumed h1b)
    {
        dim3 grid(Co / 128, (N + 127) / 128);
        gemm_mfma_kernel<<<grid, 256, 0, stream>>>(g1b, w2thi, w2tlo, h2b, N, Ch, Co,
                                                   as2, ad2, asv2, adv2);
    }
    agg2_kernel<<<(N + 3) / 4, 256, 0, stream>>>(row_start, epack, asv2, adv2, ae_loop,
                                                 h2b, out, b2, N);
}

// Round 5
// 417.446 us; speedup vs baseline: 1.0358x; 1.0358x over previous
//
#include <hip/hip_runtime.h>
#include <hip/hip_bf16.h>

// ---------------------------------------------------------------------------
// 2-layer GATConv (heads=1). N=50000, E=800000, Cin=128, Ch=256, Co=128, Ed=8.
// 8-dispatch pipeline:
//   memset | prep (W-split + we_vec) | FAT [hist+rank+aEe ∥ gemm1(64x64)] |
//   fused-scan | fill (atomic-free) | agg1 | gemm2 | agg2
// R5: R4's fat poisoned hist occupancy via the gemm's 31KB LDS (26% occ ->
// 150us). Fix: gemm1 uses 64x64 tiles (15.4KB LDS -> 8 blocks/CU, hist at
// full TLP). Also deg is padded to one counter per 64B line (deg[node*16])
// to remove atomic line-contention (was 16 nodes = ~256 RMWs per line).
// ---------------------------------------------------------------------------

#define NEG_SLOPE 0.2f

typedef unsigned short u16;
typedef short short8 __attribute__((ext_vector_type(8)));
typedef float v4f __attribute__((ext_vector_type(4)));
typedef u16 u16x4 __attribute__((ext_vector_type(4)));
typedef u16 u16x8 __attribute__((ext_vector_type(8)));

__device__ __forceinline__ u16 f2bf(float f) {
    unsigned u = __float_as_uint(f);
    return (u16)((u + 0x7fffu + ((u >> 16) & 1u)) >> 16);
}
__device__ __forceinline__ float bf2f(u16 h) {
    return __uint_as_float(((unsigned)h) << 16);
}
__device__ __forceinline__ float bf_lo(int v) { return __uint_as_float(((unsigned)v) << 16); }
__device__ __forceinline__ float bf_hi(int v) { return __uint_as_float(((unsigned)v) & 0xffff0000u); }
__device__ __forceinline__ float lrelu(float x) {
    return x >= 0.f ? x : NEG_SLOPE * x;
}
__device__ __forceinline__ int ld_acq(int* p) {
    return __hip_atomic_load(p, __ATOMIC_ACQUIRE, __HIP_MEMORY_SCOPE_AGENT);
}
__device__ __forceinline__ void st_rel(int* p, int v) {
    __hip_atomic_store(p, v, __ATOMIC_RELEASE, __HIP_MEMORY_SCOPE_AGENT);
}

// ---- prep: [blocks 0..256): W1^T / W2^T bf16 hi/lo splits
//            [block 256]: we_vec1/2 = We^T @ ae (computed once, published) ---
__global__ __launch_bounds__(256) void prep_kernel(
        const float* __restrict__ W1, u16* __restrict__ w1thi, u16* __restrict__ w1tlo,
        const float* __restrict__ W2, u16* __restrict__ w2thi, u16* __restrict__ w2tlo,
        const float* __restrict__ We1, const float* __restrict__ ae1v,
        const float* __restrict__ We2, const float* __restrict__ ae2v,
        float* __restrict__ we_vec1g, float* __restrict__ we_vec2g) {
    int tid = threadIdx.x;
    if (blockIdx.x < 256) {
        int t = blockIdx.x * 256 + tid;
        if (t < 128 * 256) {               // W1 [Cin=128][Ch=256]
            int k = t >> 8, m = t & 255;
            float v = W1[t];
            u16 h = f2bf(v);
            w1thi[(size_t)m * 128 + k] = h;
            w1tlo[(size_t)m * 128 + k] = f2bf(v - bf2f(h));
        } else {                           // W2 [Ch=256][Co=128]
            t -= 128 * 256;
            int k = t >> 7, m = t & 127;
            float v = W2[t];
            u16 h = f2bf(v);
            w2thi[(size_t)m * 256 + k] = h;
            w2tlo[(size_t)m * 256 + k] = f2bf(v - bf2f(h));
        }
        return;
    }
    // ---- we_vec: wv[j] = sum_k We1[j][k]*ae1v[k]; wv[8+j] for We2 ----
    __shared__ float wv[16];
    if (tid < 16) wv[tid] = 0.f;
    __syncthreads();
    {
        float a1 = ae1v[tid];              // Ch == 256 == blockDim
        int lane = tid & 63;
#pragma unroll
        for (int j = 0; j < 8; ++j) {
            float v = We1[j * 256 + tid] * a1;
#pragma unroll
            for (int o = 32; o; o >>= 1) v += __shfl_down(v, o);
            if (lane == 0) atomicAdd(&wv[j], v);
        }
        if (tid < 128) {
            float a2 = ae2v[tid];          // Co == 128
#pragma unroll
            for (int j = 0; j < 8; ++j) {
                float v = We2[j * 128 + tid] * a2;
#pragma unroll
                for (int o = 32; o; o >>= 1) v += __shfl_down(v, o);
                if (lane == 0) atomicAdd(&wv[8 + j], v);
            }
        }
    }
    __syncthreads();
    if (tid < 8)  we_vec1g[tid] = wv[tid];
    else if (tid < 16) we_vec2g[tid - 8] = wv[tid];
}

// ---- FAT: [blocks 0..Fb): edge hist (fetch-add -> rank, 64B-padded deg)
//           [blocks Fb..): gemm1 64x64 tiles (15.4KB LDS -> 8 blocks/CU)
#define BK 32
#define LDA 40   // 32 + 8 pad (u16)
__global__ __launch_bounds__(256) void fat1_kernel(
        // hist args
        const float* __restrict__ ea, const int* __restrict__ dst,
        float* __restrict__ mean_acc, int* __restrict__ deg,   // padded: node*16
        int* __restrict__ rank, float2* __restrict__ aEe, int E,
        const float* __restrict__ we_vec1g, const float* __restrict__ we_vec2g,
        int Fb,
        // gemm args (64x64 tile)
        const float* __restrict__ A32,
        const u16* __restrict__ Bh_g, const u16* __restrict__ Bl_g,
        u16* __restrict__ Cb, int Nrows, int K, int M,
        const float* __restrict__ av, const float* __restrict__ bv,
        float* __restrict__ as_out, float* __restrict__ ad_out, int gx) {
    __shared__ u16 Ah[64 * LDA], Bh[64 * LDA], Bl[64 * LDA];
    int tid = threadIdx.x;
    if ((int)blockIdx.x < Fb) {
        // ---- hist branch ----
        __shared__ float red[8];
        __shared__ float wv[16];
        if (tid < 16) { wv[tid] = (tid < 8) ? we_vec1g[tid] : we_vec2g[tid - 8];
                        if (tid < 8) red[tid] = 0.f; }
        __syncthreads();
        int e = (int)blockIdx.x * 256 + tid;
        float s[8] = {0.f};
        if (e < E) {
            const float4 v0 = *(const float4*)&ea[(size_t)e * 8];
            const float4 v1 = *(const float4*)&ea[(size_t)e * 8 + 4];
            int d = dst[e];
            s[0] = v0.x; s[1] = v0.y; s[2] = v0.z; s[3] = v0.w;
            s[4] = v1.x; s[5] = v1.y; s[6] = v1.z; s[7] = v1.w;
            float s1 = v0.x * wv[0] + v0.y * wv[1] + v0.z * wv[2] + v0.w * wv[3]
                     + v1.x * wv[4] + v1.y * wv[5] + v1.z * wv[6] + v1.w * wv[7];
            float s2 = v0.x * wv[8] + v0.y * wv[9] + v0.z * wv[10] + v0.w * wv[11]
                     + v1.x * wv[12] + v1.y * wv[13] + v1.z * wv[14] + v1.w * wv[15];
            aEe[e] = make_float2(s1, s2);
            rank[e] = atomicAdd(&deg[d << 4], 1);   // one counter per 64B line
        }
        int lane = tid & 63;
#pragma unroll
        for (int j = 0; j < 8; ++j) {
#pragma unroll
            for (int o = 32; o; o >>= 1) s[j] += __shfl_down(s[j], o);
            if (lane == 0) atomicAdd(&red[j], s[j]);
        }
        __syncthreads();
        if (tid < 8) atomicAdd(&mean_acc[tid], red[tid]);
        return;
    }
    // ---- gemm1 branch: 64x64 tile, wave computes 16 rows x 64 cols ---------
    int gb = (int)blockIdx.x - Fb;
    int lane = tid & 63;
    int wvx = tid >> 6;
    int l15 = lane & 15, quad = lane >> 4;
    int rb = (gb / gx) * 64;
    int cb = (gb % gx) * 64;

    v4f acc[4];
#pragma unroll
    for (int ni = 0; ni < 4; ++ni) acc[ni] = (v4f){0.f, 0.f, 0.f, 0.f};

    int sr = tid >> 2;            // 0..63
    int sc = (tid & 3) * 8;       // 0,8,16,24

    for (int kc = 0; kc < K; kc += BK) {
        int gr = rb + sr;
        u16x8 a0 = {0,0,0,0,0,0,0,0};
        if (gr < Nrows) {
            const float* pa = A32 + (size_t)gr * K + kc + sc;
            float4 f0 = *(const float4*)pa;
            float4 f1 = *(const float4*)(pa + 4);
            a0 = (u16x8){f2bf(f0.x), f2bf(f0.y), f2bf(f0.z), f2bf(f0.w),
                         f2bf(f1.x), f2bf(f1.y), f2bf(f1.z), f2bf(f1.w)};
        }
        size_t bb = (size_t)(cb + sr) * K + kc + sc;
        u16x8 b0 = *(const u16x8*)(Bh_g + bb);
        u16x8 b1 = *(const u16x8*)(Bl_g + bb);
        *(u16x8*)&Ah[sr * LDA + sc] = a0;
        *(u16x8*)&Bh[sr * LDA + sc] = b0;
        *(u16x8*)&Bl[sr * LDA + sc] = b1;
        __syncthreads();
        short8 ah = *(const short8*)&Ah[(wvx * 16 + l15) * LDA + quad * 8];
        short8 bh[4], bl[4];
#pragma unroll
        for (int ni = 0; ni < 4; ++ni) {
            int r = (ni * 16 + l15) * LDA + quad * 8;
            bh[ni] = *(const short8*)&Bh[r];
            bl[ni] = *(const short8*)&Bl[r];
        }
#pragma unroll
        for (int ni = 0; ni < 4; ++ni) {
            acc[ni] = __builtin_amdgcn_mfma_f32_16x16x32_bf16(ah, bh[ni], acc[ni], 0, 0, 0);
            acc[ni] = __builtin_amdgcn_mfma_f32_16x16x32_bf16(ah, bl[ni], acc[ni], 0, 0, 0);
        }
        __syncthreads();
    }
#pragma unroll
    for (int ni = 0; ni < 4; ++ni)
#pragma unroll
        for (int reg = 0; reg < 4; ++reg) {
            int row = rb + wvx * 16 + quad * 4 + reg;
            if (row < Nrows)
                Cb[(size_t)row * M + cb + ni * 16 + l15] = f2bf(acc[ni][reg]);
        }
    float sd[4] = {}, dd[4] = {};
#pragma unroll
    for (int ni = 0; ni < 4; ++ni) {
        int col = cb + ni * 16 + l15;
        float a = av[col], b = bv[col];
#pragma unroll
        for (int reg = 0; reg < 4; ++reg) {
            sd[reg] += acc[ni][reg] * a;
            dd[reg] += acc[ni][reg] * b;
        }
    }
#pragma unroll
    for (int off = 1; off < 16; off <<= 1)
#pragma unroll
        for (int reg = 0; reg < 4; ++reg) {
            sd[reg] += __shfl_xor(sd[reg], off);
            dd[reg] += __shfl_xor(dd[reg], off);
        }
    if (l15 == 0) {
        int row0 = rb + wvx * 16 + quad * 4;
#pragma unroll
        for (int reg = 0; reg < 4; ++reg)
            if (row0 + reg < Nrows) {
                atomicAdd(as_out + row0 + reg, sd[reg]);
                atomicAdd(ad_out + row0 + reg, dd[reg]);
            }
    }
}

// ---- fused single-kernel exclusive scan (196 blocks, all co-resident) ------
// deg is 64B-padded: element i lives at deg[i*16].
__global__ __launch_bounds__(256) void scan_fused_kernel(
        const int* __restrict__ deg, int* __restrict__ row_start,
        int* __restrict__ partials, int* __restrict__ pprefix,
        int* __restrict__ gcount, int* __restrict__ gflag, int N, int n,
        const float* __restrict__ mean_acc, float Einv,
        const float* __restrict__ we_vec1, const float* __restrict__ we_vec2,
        float* __restrict__ ae_loop) {
    __shared__ int s[256];
    __shared__ int amLast, bprefix;
    int t = threadIdx.x, bid = blockIdx.x;
    int i = bid * 256 + t;
    int v = (i < N) ? deg[i << 4] : 0;
    s[t] = v; __syncthreads();
    for (int off = 1; off < 256; off <<= 1) {
        int u = (t >= off) ? s[t - off] : 0;
        __syncthreads();
        s[t] += u;
        __syncthreads();
    }
    int incl = s[t];
    int total = s[255];
    if (t == 0) {
        partials[bid] = total;
        __threadfence();
        int c = __hip_atomic_fetch_add(gcount, 1, __ATOMIC_ACQ_REL, __HIP_MEMORY_SCOPE_AGENT);
        amLast = (c == (int)gridDim.x - 1);
    }
    __syncthreads();
    if (amLast) {
        int G = gridDim.x;
        int pv = (t < G) ? ld_acq(&partials[t]) : 0;
        __syncthreads();           // s[] reuse
        s[t] = pv; __syncthreads();
        for (int off = 1; off < 256; off <<= 1) {
            int u = (t >= off) ? s[t - off] : 0;
            __syncthreads();
            s[t] += u;
            __syncthreads();
        }
        if (t < G) pprefix[t] = s[t] - pv;
        if (t == 0) {
            float s1 = 0.f, s2 = 0.f;
#pragma unroll
            for (int j = 0; j < 8; ++j) {
                float m = mean_acc[j] * Einv;
                s1 += m * we_vec1[j];
                s2 += m * we_vec2[j];
            }
            ae_loop[0] = s1; ae_loop[1] = s2;
        }
        __threadfence();
        __syncthreads();
        if (t == 0) st_rel(gflag, 1);
    }
    if (t == 0) {
        while (ld_acq(gflag) == 0) __builtin_amdgcn_s_sleep(2);
        bprefix = ld_acq(&pprefix[bid]);
    }
    __syncthreads();
    int ex = bprefix + incl - v;
    if (i < n) row_start[i] = ex;
}

// ---- CSR fill: atomic-free (slot = row_start[dst] + rank), max TLP ---------
__global__ __launch_bounds__(256) void fill_kernel(
        const int* __restrict__ src, const int* __restrict__ dst,
        const float2* __restrict__ aEe, const int* __restrict__ row_start,
        const int* __restrict__ rank,
        float4* __restrict__ epack, int E) {
    int e = blockIdx.x * 256 + threadIdx.x;
    if (e >= E) return;
    int d = dst[e];
    int idx = row_start[d] + rank[e];
    float2 a = aEe[e];
    epack[idx] = make_float4(__int_as_float(src[e]), a.x, a.y, 0.f);
}

// ---- gemm2: 128x128, A already bf16 ----------------------------------------
#define LDA2 40
__global__ __launch_bounds__(256) void gemm_mfma_kernel(
        const u16* __restrict__ A_g,
        const u16* __restrict__ Bh_g, const u16* __restrict__ Bl_g,
        u16* __restrict__ Cb, int Nrows, int K, int M,
        const float* __restrict__ av, const float* __restrict__ bv,
        float* __restrict__ as_out, float* __restrict__ ad_out) {
    __shared__ u16 Ah[128 * LDA2], Bh[128 * LDA2], Bl[128 * LDA2];
    int tid = threadIdx.x;
    int lane = tid & 63;
    int wv = tid >> 6;
    int wm = wv >> 1, wn = wv & 1;
    int l15 = lane & 15, quad = lane >> 4;
    int rb = blockIdx.y * 128;
    int cb = blockIdx.x * 128;

    v4f acc[4][4];
#pragma unroll
    for (int mi = 0; mi < 4; ++mi)
#pragma unroll
        for (int ni = 0; ni < 4; ++ni) acc[mi][ni] = (v4f){0.f, 0.f, 0.f, 0.f};

    int sr = tid >> 1;
    int sc = (tid & 1) * 16;

    for (int kc = 0; kc < K; kc += BK) {
        int gr = rb + sr;
        u16x8 a0 = {0,0,0,0,0,0,0,0}, a1 = {0,0,0,0,0,0,0,0};
        if (gr < Nrows) {
            size_t ba = (size_t)gr * K + kc + sc;
            a0 = *(const u16x8*)(A_g + ba);
            a1 = *(const u16x8*)(A_g + ba + 8);
        }
        size_t bb = (size_t)(cb + sr) * K + kc + sc;
        u16x8 b0 = *(const u16x8*)(Bh_g + bb);
        u16x8 b1 = *(const u16x8*)(Bh_g + bb + 8);
        u16x8 b2 = *(const u16x8*)(Bl_g + bb);
        u16x8 b3 = *(const u16x8*)(Bl_g + bb + 8);
        *(u16x8*)&Ah[sr * LDA2 + sc] = a0;
        *(u16x8*)&Ah[sr * LDA2 + sc + 8] = a1;
        *(u16x8*)&Bh[sr * LDA2 + sc] = b0;
        *(u16x8*)&Bh[sr * LDA2 + sc + 8] = b1;
        *(u16x8*)&Bl[sr * LDA2 + sc] = b2;
        *(u16x8*)&Bl[sr * LDA2 + sc + 8] = b3;
        __syncthreads();
        short8 ah[4], bh[4], bl[4];
#pragma unroll
        for (int mi = 0; mi < 4; ++mi)
            ah[mi] = *(const short8*)&Ah[(wm * 64 + mi * 16 + l15) * LDA2 + quad * 8];
#pragma unroll
        for (int ni = 0; ni < 4; ++ni) {
            int r = (wn * 64 + ni * 16 + l15) * LDA2 + quad * 8;
            bh[ni] = *(const short8*)&Bh[r];
            bl[ni] = *(const short8*)&Bl[r];
        }
#pragma unroll
        for (int mi = 0; mi < 4; ++mi)
#pragma unroll
            for (int ni = 0; ni < 4; ++ni) {
                acc[mi][ni] = __builtin_amdgcn_mfma_f32_16x16x32_bf16(ah[mi], bh[ni], acc[mi][ni], 0, 0, 0);
                acc[mi][ni] = __builtin_amdgcn_mfma_f32_16x16x32_bf16(ah[mi], bl[ni], acc[mi][ni], 0, 0, 0);
            }
        __syncthreads();
    }
#pragma unroll
    for (int mi = 0; mi < 4; ++mi)
#pragma unroll
        for (int ni = 0; ni < 4; ++ni)
#pragma unroll
            for (int reg = 0; reg < 4; ++reg) {
                int row = rb + wm * 64 + mi * 16 + quad * 4 + reg;
                if (row < Nrows)
                    Cb[(size_t)row * M + cb + wn * 64 + ni * 16 + l15] = f2bf(acc[mi][ni][reg]);
            }
    float sd[4][4] = {}, dd[4][4] = {};
#pragma unroll
    for (int ni = 0; ni < 4; ++ni) {
        int col = cb + wn * 64 + ni * 16 + l15;
        float a = av[col], b = bv[col];
#pragma unroll
        for (int mi = 0; mi < 4; ++mi)
#pragma unroll
            for (int reg = 0; reg < 4; ++reg) {
                sd[mi][reg] += acc[mi][ni][reg] * a;
                dd[mi][reg] += acc[mi][ni][reg] * b;
            }
    }
#pragma unroll
    for (int off = 1; off < 16; off <<= 1)
#pragma unroll
        for (int mi = 0; mi < 4; ++mi)
#pragma unroll
            for (int reg = 0; reg < 4; ++reg) {
                sd[mi][reg] += __shfl_xor(sd[mi][reg], off);
                dd[mi][reg] += __shfl_xor(dd[mi][reg], off);
            }
    if (l15 == 0)
#pragma unroll
        for (int mi = 0; mi < 4; ++mi) {
            int row0 = rb + wm * 64 + mi * 16 + quad * 4;
#pragma unroll
            for (int reg = 0; reg < 4; ++reg)
                if (row0 + reg < Nrows) {
                    atomicAdd(as_out + row0 + reg, sd[mi][reg]);
                    atomicAdd(ad_out + row0 + reg, dd[mi][reg]);
                }
        }
}

// ---- single-pass FLASH softmax-aggregation, L1 (C=256), wave per node ------
__global__ __launch_bounds__(256) void agg1_kernel(const int* __restrict__ row_start,
                                                   const float4* __restrict__ epack,
                                                   const float* __restrict__ asv,
                                                   const float* __restrict__ adv,
                                                   const float* __restrict__ ae_loop,
                                                   const u16* __restrict__ Hb,
                                                   u16* __restrict__ ohi,
                                                   const float* __restrict__ bias, int N) {
    __shared__ float2 xch[4][64];
    int lane = threadIdx.x & 63;
    int wvi = threadIdx.x >> 6;
    int node = blockIdx.x * 4 + wvi;
    if (node >= N) return;
    int st = row_start[node], en = row_start[node + 1];
    float ad = adv[node];
    float aloop = lrelu(asv[node] + ad + ae_loop[0]);
    float m = aloop, sum = 1.f;
    float acc0, acc1, acc2, acc3;
    {
        int2 hv = *(const int2*)(Hb + (size_t)node * 256 + lane * 4);
        acc0 = bf_lo(hv.x); acc1 = bf_hi(hv.x);
        acc2 = bf_lo(hv.y); acc3 = bf_hi(hv.y);
    }
    for (int base = st; base < en; base += 64) {
        int i = base + lane;
        float al = -3.0e38f; int sreg = 0;
        if (i < en) {
            float4 ep = epack[i];
            sreg = __float_as_int(ep.x);
            al = lrelu(asv[sreg] + ad + ep.y);
        }
        float cm = al;
#pragma unroll
        for (int o = 1; o < 64; o <<= 1) cm = fmaxf(cm, __shfl_xor(cm, o));
        if (cm > m) {
            float sc = __expf(m - cm);
            acc0 *= sc; acc1 *= sc; acc2 *= sc; acc3 *= sc;
            sum *= sc; m = cm;
        }
        float w = (i < en) ? __expf(al - m) : 0.f;
        float wsum = w;
#pragma unroll
        for (int o = 1; o < 64; o <<= 1) wsum += __shfl_xor(wsum, o);
        sum += wsum;
        xch[wvi][lane] = make_float2(w, __int_as_float(sreg));
        int cnt = min(64, en - base);
        int j = 0;
        for (; j + 8 <= cnt; j += 8) {
            float2 e[8]; int2 h[8];
#pragma unroll
            for (int q = 0; q < 8; ++q) e[q] = xch[wvi][j + q];
#pragma unroll
            for (int q = 0; q < 8; ++q)
                h[q] = *(const int2*)(Hb + (size_t)__float_as_int(e[q].y) * 256 + lane * 4);
#pragma unroll
            for (int q = 0; q < 8; ++q) {
                acc0 += e[q].x * bf_lo(h[q].x); acc1 += e[q].x * bf_hi(h[q].x);
                acc2 += e[q].x * bf_lo(h[q].y); acc3 += e[q].x * bf_hi(h[q].y);
            }
        }
        for (; j + 4 <= cnt; j += 4) {
            float2 e0 = xch[wvi][j], e1 = xch[wvi][j + 1];
            float2 e2 = xch[wvi][j + 2], e3 = xch[wvi][j + 3];
            int2 h0 = *(const int2*)(Hb + (size_t)__float_as_int(e0.y) * 256 + lane * 4);
            int2 h1 = *(const int2*)(Hb + (size_t)__float_as_int(e1.y) * 256 + lane * 4);
            int2 h2 = *(const int2*)(Hb + (size_t)__float_as_int(e2.y) * 256 + lane * 4);
            int2 h3 = *(const int2*)(Hb + (size_t)__float_as_int(e3.y) * 256 + lane * 4);
            acc0 += e0.x * bf_lo(h0.x) + e1.x * bf_lo(h1.x) + e2.x * bf_lo(h2.x) + e3.x * bf_lo(h3.x);
            acc1 += e0.x * bf_hi(h0.x) + e1.x * bf_hi(h1.x) + e2.x * bf_hi(h2.x) + e3.x * bf_hi(h3.x);
            acc2 += e0.x * bf_lo(h0.y) + e1.x * bf_lo(h1.y) + e2.x * bf_lo(h2.y) + e3.x * bf_lo(h3.y);
            acc3 += e0.x * bf_hi(h0.y) + e1.x * bf_hi(h1.y) + e2.x * bf_hi(h2.y) + e3.x * bf_hi(h3.y);
        }
        for (; j < cnt; ++j) {
            float2 e0 = xch[wvi][j];
            int2 h0 = *(const int2*)(Hb + (size_t)__float_as_int(e0.y) * 256 + lane * 4);
            acc0 += e0.x * bf_lo(h0.x); acc1 += e0.x * bf_hi(h0.x);
            acc2 += e0.x * bf_lo(h0.y); acc3 += e0.x * bf_hi(h0.y);
        }
    }
    float inv = 1.f / sum;
    const float4 bvv = *(const float4*)(bias + lane * 4);
    float t0 = acc0 * inv + bvv.x, t1 = acc1 * inv + bvv.y;
    float t2 = acc2 * inv + bvv.z, t3 = acc3 * inv + bvv.w;
    t0 = t0 > 0.f ? t0 : 0.f; t1 = t1 > 0.f ? t1 : 0.f;
    t2 = t2 > 0.f ? t2 : 0.f; t3 = t3 > 0.f ? t3 : 0.f;
    u16x4 h;
    h.x = f2bf(t0); h.y = f2bf(t1); h.z = f2bf(t2); h.w = f2bf(t3);
    *(u16x4*)(ohi + (size_t)node * 256 + lane * 4) = h;
}

// ---- single-pass FLASH softmax-aggregation, L2 (C=128) ---------------------
__global__ __launch_bounds__(256) void agg2_kernel(const int* __restrict__ row_start,
                                                   const float4* __restrict__ epack,
                                                   const float* __restrict__ asv,
                                                   const float* __restrict__ adv,
                                                   const float* __restrict__ ae_loop,
                                                   const u16* __restrict__ Hb,
                                                   float* __restrict__ out,
                                                   const float* __restrict__ bias, int N) {
    __shared__ float2 xch[4][64];
    int lane = threadIdx.x & 63;
    int wvi = threadIdx.x >> 6;
    int node = blockIdx.x * 4 + wvi;
    if (node >= N) return;
    int st = row_start[node], en = row_start[node + 1];
    float ad = adv[node];
    float aloop = lrelu(asv[node] + ad + ae_loop[1]);
    float m = aloop, sum = 1.f;
    float acc0, acc1;
    {
        int hv = *(const int*)(Hb + (size_t)node * 128 + lane * 2);
        acc0 = bf_lo(hv); acc1 = bf_hi(hv);
    }
    for (int base = st; base < en; base += 64) {
        int i = base + lane;
        float al = -3.0e38f; int sreg = 0;
        if (i < en) {
            float4 ep = epack[i];
            sreg = __float_as_int(ep.x);
            al = lrelu(asv[sreg] + ad + ep.z);
        }
        float cm = al;
#pragma unroll
        for (int o = 1; o < 64; o <<= 1) cm = fmaxf(cm, __shfl_xor(cm, o));
        if (cm > m) {
            float sc = __expf(m - cm);
            acc0 *= sc; acc1 *= sc;
            sum *= sc; m = cm;
        }
        float w = (i < en) ? __expf(al - m) : 0.f;
        float wsum = w;
#pragma unroll
        for (int o = 1; o < 64; o <<= 1) wsum += __shfl_xor(wsum, o);
        sum += wsum;
        xch[wvi][lane] = make_float2(w, __int_as_float(sreg));
        int cnt = min(64, en - base);
        int j = 0;
        for (; j + 8 <= cnt; j += 8) {
            float2 e[8]; int h[8];
#pragma unroll
            for (int q = 0; q < 8; ++q) e[q] = xch[wvi][j + q];
#pragma unroll
            for (int q = 0; q < 8; ++q)
                h[q] = *(const int*)(Hb + (size_t)__float_as_int(e[q].y) * 128 + lane * 2);
#pragma unroll
            for (int q = 0; q < 8; ++q) {
                acc0 += e[q].x * bf_lo(h[q]); acc1 += e[q].x * bf_hi(h[q]);
            }
        }
        for (; j + 4 <= cnt; j += 4) {
            float2 e0 = xch[wvi][j], e1 = xch[wvi][j + 1];
            float2 e2 = xch[wvi][j + 2], e3 = xch[wvi][j + 3];
            int h0 = *(const int*)(Hb + (size_t)__float_as_int(e0.y) * 128 + lane * 2);
            int h1 = *(const int*)(Hb + (size_t)__float_as_int(e1.y) * 128 + lane * 2);
            int h2 = *(const int*)(Hb + (size_t)__float_as_int(e2.y) * 128 + lane * 2);
            int h3 = *(const int*)(Hb + (size_t)__float_as_int(e3.y) * 128 + lane * 2);
            acc0 += e0.x * bf_lo(h0) + e1.x * bf_lo(h1) + e2.x * bf_lo(h2) + e3.x * bf_lo(h3);
            acc1 += e0.x * bf_hi(h0) + e1.x * bf_hi(h1) + e2.x * bf_hi(h2) + e3.x * bf_hi(h3);
        }
        for (; j < cnt; ++j) {
            float2 e0 = xch[wvi][j];
            int h0 = *(const int*)(Hb + (size_t)__float_as_int(e0.y) * 128 + lane * 2);
            acc0 += e0.x * bf_lo(h0); acc1 += e0.x * bf_hi(h0);
        }
    }
    float inv = 1.f / sum;
    size_t o = (size_t)node * 128 + lane * 2;
    out[o]     = acc0 * inv + bias[lane * 2];
    out[o + 1] = acc1 * inv + bias[lane * 2 + 1];
}

extern "C" void kernel_launch(void* const* d_in, const int* in_sizes, int n_in,
                              void* d_out, int out_size, void* d_ws, size_t ws_size,
                              hipStream_t stream) {
    const int Cin = 128, Ch = 256, Co = 128;
    const int N = in_sizes[0] / Cin;        // 50000
    const int E = in_sizes[1] / 2;          // 800000

    const float* x   = (const float*)d_in[0];
    const int*   src = (const int*)d_in[1];
    const int*   dst = src + E;
    const float* ea  = (const float*)d_in[2];
    const float* W1  = (const float*)d_in[3];
    const float* We1 = (const float*)d_in[4];
    const float* as1 = (const float*)d_in[5];
    const float* ad1 = (const float*)d_in[6];
    const float* ae1 = (const float*)d_in[7];
    const float* b1  = (const float*)d_in[8];
    const float* W2  = (const float*)d_in[9];
    const float* We2 = (const float*)d_in[10];
    const float* as2 = (const float*)d_in[11];
    const float* ad2 = (const float*)d_in[12];
    const float* ae2 = (const float*)d_in[13];
    const float* b2  = (const float*)d_in[14];
    float* out = (float*)d_out;

    // workspace layout (4-byte units)
    float* ws = (float*)d_ws;
    size_t off = 0;
    u16* h1b = (u16*)(ws + off); off += (size_t)N * Ch / 2;   // bf16 h (reused as h2b)
    u16* g1b = (u16*)(ws + off); off += (size_t)N * Ch / 2;   // agg1 output (gemm2 A)
    float4* epack = (float4*)(ws + off); off += (size_t)E * 4;  // packed CSR edges
    float2* aEe   = (float2*)(ws + off); off += (size_t)E * 2;  // edge-order a_e
    int* rank     = (int*)(ws + off); off += (size_t)E;         // per-edge rank
    int* row_start = (int*)(ws + off); off += (size_t)N + 1;
    int* partials  = (int*)(ws + off); off += 256;
    int* pprefix   = (int*)(ws + off); off += 256;
    u16* w1thi = (u16*)(ws + off); off += (size_t)Cin * Ch / 2;
    u16* w1tlo = (u16*)(ws + off); off += (size_t)Cin * Ch / 2;
    u16* w2thi = (u16*)(ws + off); off += (size_t)Ch * Co / 2;
    u16* w2tlo = (u16*)(ws + off); off += (size_t)Ch * Co / 2;
    // contiguous zero-region: deg(padded 64B/node) | asv1 adv1 asv2 adv2 | misc | sync
    int*   deg  = (int*)(ws + off); off += (size_t)16 * (N + 1);
    float* asv1 = ws + off; off += (size_t)N;
    float* adv1 = ws + off; off += (size_t)N;
    float* asv2 = ws + off; off += (size_t)N;
    float* adv2 = ws + off; off += (size_t)N;
    float* misc = ws + off; off += 32;
    float* mean_acc = misc;
    float* we_vec1  = misc + 8;
    float* we_vec2  = misc + 16;
    float* ae_loop  = misc + 24;
    int* gcount = (int*)(ws + off); off += 1;
    int* gflag  = (int*)(ws + off); off += 1;

    const int n1 = N + 1;
    const int nscan = (n1 + 255) / 256;   // 196 blocks <= 256 CUs (co-resident)

    // one memset zeroes padded-deg + 4 dot-buffers + misc + sync flags
    hipMemsetAsync(deg, 0, ((size_t)20 * N + 50) * sizeof(float), stream);

    // ---- prep: W splits (256 blocks) + we_vec (1 block) --------------------
    prep_kernel<<<257, 256, 0, stream>>>(
        W1, w1thi, w1tlo, W2, w2thi, w2tlo,
        We1, ae1, We2, ae2, we_vec1, we_vec2);

    // ---- FAT: hist (3125 blocks, first) || gemm1 64x64 (3128 blocks) -------
    {
        int Fb = (E + 255) / 256;                // 3125
        int gx = Ch / 64;                        // 4
        int Gg = gx * ((N + 63) / 64);           // 3128
        fat1_kernel<<<Fb + Gg, 256, 0, stream>>>(
            ea, dst, mean_acc, deg, rank, aEe, E, we_vec1, we_vec2, Fb,
            x, w1thi, w1tlo, h1b, N, Cin, Ch, as1, ad1, asv1, adv1, gx);
    }

    // ---- fused scan (+ae_loop) ---------------------------------------------
    scan_fused_kernel<<<nscan, 256, 0, stream>>>(
        deg, row_start, partials, pprefix, gcount, gflag, N, n1,
        mean_acc, 1.0f / (float)E, we_vec1, we_vec2, ae_loop);

    // ---- CSR fill: atomic-free ---------------------------------------------
    fill_kernel<<<(E + 255) / 256, 256, 0, stream>>>(src, dst, aEe, row_start,
                                                     rank, epack, E);

    agg1_kernel<<<(N + 3) / 4, 256, 0, stream>>>(row_start, epack, asv1, adv1, ae_loop,
                                                 h1b, g1b, b1, N);

    // ---- layer 2 ----------------------------------------------------------
    u16* h2b = h1b; // reuse (agg1 consumed h1b)
    {
        dim3 grid(Co / 128, (N + 127) / 128);
        gemm_mfma_kernel<<<grid, 256, 0, stream>>>(g1b, w2thi, w2tlo, h2b, N, Ch, Co,
                                                   as2, ad2, asv2, adv2);
    }
    agg2_kernel<<<(N + 3) / 4, 256, 0, stream>>>(row_start, epack, asv2, adv2, ae_loop,
                                                 h2b, out, b2, N);
}

// Round 6
// 349.830 us; speedup vs baseline: 1.2360x; 1.1933x over previous
//
#include <hip/hip_runtime.h>
#include <hip/hip_bf16.h>

// ---------------------------------------------------------------------------
// 2-layer GATConv (heads=1). N=50000, E=800000, Cin=128, Ch=256, Co=128, Ed=8.
// 8-dispatch pipeline:
//   memset | prep (W-split + we_vec) | FAT [hist+rank+aEe ⟂ gemm1(64x128),
//   block-interleaved] | fused-scan | fill (atomic-free) | agg1 | gemm2 | agg2
// R6: revert R5's measured regressions (deg padding -> unpadded; 64x64 tiles
// -> 64x128, gx=2) and fix the overlap scheduling: hist and gemm blocks are
// 1:1 interleaved in blockIdx so both are co-resident on every CU for the
// whole kernel. Hist (atomic-throughput-bound at ~38% wave occupancy, R2's
// proven regime) saturates the atomic pipe; gemm MFMA fills the idle issue
// slots. Hist keeps the grid-stride loop (ILP) + returning fetch-add (rank
// feeds the atomic-free CSR fill, R3's win).
// ---------------------------------------------------------------------------

#define NEG_SLOPE 0.2f

typedef unsigned short u16;
typedef short short8 __attribute__((ext_vector_type(8)));
typedef float v4f __attribute__((ext_vector_type(4)));
typedef u16 u16x4 __attribute__((ext_vector_type(4)));
typedef u16 u16x8 __attribute__((ext_vector_type(8)));

__device__ __forceinline__ u16 f2bf(float f) {
    unsigned u = __float_as_uint(f);
    return (u16)((u + 0x7fffu + ((u >> 16) & 1u)) >> 16);
}
__device__ __forceinline__ float bf2f(u16 h) {
    return __uint_as_float(((unsigned)h) << 16);
}
__device__ __forceinline__ float bf_lo(int v) { return __uint_as_float(((unsigned)v) << 16); }
__device__ __forceinline__ float bf_hi(int v) { return __uint_as_float(((unsigned)v) & 0xffff0000u); }
__device__ __forceinline__ float lrelu(float x) {
    return x >= 0.f ? x : NEG_SLOPE * x;
}
__device__ __forceinline__ int ld_acq(int* p) {
    return __hip_atomic_load(p, __ATOMIC_ACQUIRE, __HIP_MEMORY_SCOPE_AGENT);
}
__device__ __forceinline__ void st_rel(int* p, int v) {
    __hip_atomic_store(p, v, __ATOMIC_RELEASE, __HIP_MEMORY_SCOPE_AGENT);
}

// ---- prep: [blocks 0..256): W1^T / W2^T bf16 hi/lo splits
//            [block 256]: we_vec1/2 = We^T @ ae (computed once, published) ---
__global__ __launch_bounds__(256) void prep_kernel(
        const float* __restrict__ W1, u16* __restrict__ w1thi, u16* __restrict__ w1tlo,
        const float* __restrict__ W2, u16* __restrict__ w2thi, u16* __restrict__ w2tlo,
        const float* __restrict__ We1, const float* __restrict__ ae1v,
        const float* __restrict__ We2, const float* __restrict__ ae2v,
        float* __restrict__ we_vec1g, float* __restrict__ we_vec2g) {
    int tid = threadIdx.x;
    if (blockIdx.x < 256) {
        int t = blockIdx.x * 256 + tid;
        if (t < 128 * 256) {               // W1 [Cin=128][Ch=256]
            int k = t >> 8, m = t & 255;
            float v = W1[t];
            u16 h = f2bf(v);
            w1thi[(size_t)m * 128 + k] = h;
            w1tlo[(size_t)m * 128 + k] = f2bf(v - bf2f(h));
        } else {                           // W2 [Ch=256][Co=128]
            t -= 128 * 256;
            int k = t >> 7, m = t & 127;
            float v = W2[t];
            u16 h = f2bf(v);
            w2thi[(size_t)m * 256 + k] = h;
            w2tlo[(size_t)m * 256 + k] = f2bf(v - bf2f(h));
        }
        return;
    }
    // ---- we_vec: wv[j] = sum_k We1[j][k]*ae1v[k]; wv[8+j] for We2 ----
    __shared__ float wv[16];
    if (tid < 16) wv[tid] = 0.f;
    __syncthreads();
    {
        float a1 = ae1v[tid];              // Ch == 256 == blockDim
        int lane = tid & 63;
#pragma unroll
        for (int j = 0; j < 8; ++j) {
            float v = We1[j * 256 + tid] * a1;
#pragma unroll
            for (int o = 32; o; o >>= 1) v += __shfl_down(v, o);
            if (lane == 0) atomicAdd(&wv[j], v);
        }
        if (tid < 128) {
            float a2 = ae2v[tid];          // Co == 128
#pragma unroll
            for (int j = 0; j < 8; ++j) {
                float v = We2[j * 128 + tid] * a2;
#pragma unroll
                for (int o = 32; o; o >>= 1) v += __shfl_down(v, o);
                if (lane == 0) atomicAdd(&wv[8 + j], v);
            }
        }
    }
    __syncthreads();
    if (tid < 8)  we_vec1g[tid] = wv[tid];
    else if (tid < 16) we_vec2g[tid - 8] = wv[tid];
}

// ---- FAT: hist (grid-stride, Fb blocks) 1:1-interleaved with gemm1 64x128 --
// blockIdx mapping: bid < 2*min(Fb,Gg): even->hist(bid>>1), odd->gemm(bid>>1);
// remainder -> whichever type is larger.
#define BK 32
#define LDA 40   // 32 + 8 pad (u16)
__global__ __launch_bounds__(256) void fat1_kernel(
        // hist args
        const float* __restrict__ ea, const int* __restrict__ dst,
        float* __restrict__ mean_acc, int* __restrict__ deg,
        int* __restrict__ rank, float2* __restrict__ aEe, int E,
        const float* __restrict__ we_vec1g, const float* __restrict__ we_vec2g,
        int Fb, int Gg,
        // gemm args (64 rows x 128 cols tile)
        const float* __restrict__ A32,
        const u16* __restrict__ Bh_g, const u16* __restrict__ Bl_g,
        u16* __restrict__ Cb, int Nrows, int K, int M,
        const float* __restrict__ av, const float* __restrict__ bv,
        float* __restrict__ as_out, float* __restrict__ ad_out, int gx) {
    __shared__ u16 Ah[64 * LDA];          // 5.1 KB
    __shared__ u16 Bh[128 * LDA];         // 10.2 KB
    __shared__ u16 Bl[128 * LDA];         // 10.2 KB  -> 25.6 KB total, 6 blk/CU
    __shared__ float red[8];
    int tid = threadIdx.x;
    int bid = (int)blockIdx.x;
    int mn = Fb < Gg ? Fb : Gg;
    int hid = -1, gid = -1;
    if (bid < 2 * mn) {
        if ((bid & 1) == 0) hid = bid >> 1; else gid = bid >> 1;
    } else {
        int rem = bid - 2 * mn;
        if (Fb > Gg) hid = mn + rem; else gid = mn + rem;
    }
    if (hid >= 0) {
        // ---- hist branch: grid-stride edges, returning fetch-add ----
        float wv[16];
#pragma unroll
        for (int j = 0; j < 8; ++j) { wv[j] = we_vec1g[j]; wv[8 + j] = we_vec2g[j]; }
        if (tid < 8) red[tid] = 0.f;
        __syncthreads();
        float s[8] = {0.f};
        int stride = Fb * 256;
        for (int e = hid * 256 + tid; e < E; e += stride) {
            int d = dst[e];
            const float4 v0 = *(const float4*)&ea[(size_t)e * 8];
            const float4 v1 = *(const float4*)&ea[(size_t)e * 8 + 4];
            s[0] += v0.x; s[1] += v0.y; s[2] += v0.z; s[3] += v0.w;
            s[4] += v1.x; s[5] += v1.y; s[6] += v1.z; s[7] += v1.w;
            float s1 = v0.x * wv[0] + v0.y * wv[1] + v0.z * wv[2] + v0.w * wv[3]
                     + v1.x * wv[4] + v1.y * wv[5] + v1.z * wv[6] + v1.w * wv[7];
            float s2 = v0.x * wv[8] + v0.y * wv[9] + v0.z * wv[10] + v0.w * wv[11]
                     + v1.x * wv[12] + v1.y * wv[13] + v1.z * wv[14] + v1.w * wv[15];
            aEe[e] = make_float2(s1, s2);
            rank[e] = atomicAdd(&deg[d], 1);   // arrival rank (unpadded deg)
        }
        int lane = tid & 63;
#pragma unroll
        for (int j = 0; j < 8; ++j) {
#pragma unroll
            for (int o = 32; o; o >>= 1) s[j] += __shfl_down(s[j], o);
            if (lane == 0) atomicAdd(&red[j], s[j]);
        }
        __syncthreads();
        if (tid < 8) atomicAdd(&mean_acc[tid], red[tid]);
        return;
    }
    // ---- gemm1 branch: 64x128 tile, 4 waves, each wave 16 rows x 128 cols --
    int lane = tid & 63;
    int wvx = tid >> 6;
    int l15 = lane & 15, quad = lane >> 4;
    int rb = (gid / gx) * 64;
    int cb = (gid % gx) * 128;

    v4f acc[8];
#pragma unroll
    for (int ni = 0; ni < 8; ++ni) acc[ni] = (v4f){0.f, 0.f, 0.f, 0.f};

    int sr  = tid >> 2;            // 0..63  (A rows)
    int sc  = (tid & 3) * 8;       // 0,8,16,24
    int sr2 = tid >> 1;            // 0..127 (B rows)
    int sc2 = (tid & 1) * 16;      // 0,16

    for (int kc = 0; kc < K; kc += BK) {
        int gr = rb + sr;
        u16x8 a0 = {0,0,0,0,0,0,0,0};
        if (gr < Nrows) {
            const float* pa = A32 + (size_t)gr * K + kc + sc;
            float4 f0 = *(const float4*)pa;
            float4 f1 = *(const float4*)(pa + 4);
            a0 = (u16x8){f2bf(f0.x), f2bf(f0.y), f2bf(f0.z), f2bf(f0.w),
                         f2bf(f1.x), f2bf(f1.y), f2bf(f1.z), f2bf(f1.w)};
        }
        size_t bb = (size_t)(cb + sr2) * K + kc + sc2;
        u16x8 b0 = *(const u16x8*)(Bh_g + bb);
        u16x8 b1 = *(const u16x8*)(Bh_g + bb + 8);
        u16x8 b2 = *(const u16x8*)(Bl_g + bb);
        u16x8 b3 = *(const u16x8*)(Bl_g + bb + 8);
        *(u16x8*)&Ah[sr * LDA + sc] = a0;
        *(u16x8*)&Bh[sr2 * LDA + sc2] = b0;
        *(u16x8*)&Bh[sr2 * LDA + sc2 + 8] = b1;
        *(u16x8*)&Bl[sr2 * LDA + sc2] = b2;
        *(u16x8*)&Bl[sr2 * LDA + sc2 + 8] = b3;
        __syncthreads();
        short8 ah = *(const short8*)&Ah[(wvx * 16 + l15) * LDA + quad * 8];
#pragma unroll
        for (int ni = 0; ni < 8; ++ni) {
            int r = (ni * 16 + l15) * LDA + quad * 8;
            short8 bhf = *(const short8*)&Bh[r];
            short8 blf = *(const short8*)&Bl[r];
            acc[ni] = __builtin_amdgcn_mfma_f32_16x16x32_bf16(ah, bhf, acc[ni], 0, 0, 0);
            acc[ni] = __builtin_amdgcn_mfma_f32_16x16x32_bf16(ah, blf, acc[ni], 0, 0, 0);
        }
        __syncthreads();
    }
#pragma unroll
    for (int ni = 0; ni < 8; ++ni)
#pragma unroll
        for (int reg = 0; reg < 4; ++reg) {
            int row = rb + wvx * 16 + quad * 4 + reg;
            if (row < Nrows)
                Cb[(size_t)row * M + cb + ni * 16 + l15] = f2bf(acc[ni][reg]);
        }
    float sd[4] = {}, dd[4] = {};
#pragma unroll
    for (int ni = 0; ni < 8; ++ni) {
        int col = cb + ni * 16 + l15;
        float a = av[col], b = bv[col];
#pragma unroll
        for (int reg = 0; reg < 4; ++reg) {
            sd[reg] += acc[ni][reg] * a;
            dd[reg] += acc[ni][reg] * b;
        }
    }
#pragma unroll
    for (int off = 1; off < 16; off <<= 1)
#pragma unroll
        for (int reg = 0; reg < 4; ++reg) {
            sd[reg] += __shfl_xor(sd[reg], off);
            dd[reg] += __shfl_xor(dd[reg], off);
        }
    if (l15 == 0) {
        int row0 = rb + wvx * 16 + quad * 4;
#pragma unroll
        for (int reg = 0; reg < 4; ++reg)
            if (row0 + reg < Nrows) {
                atomicAdd(as_out + row0 + reg, sd[reg]);
                atomicAdd(ad_out + row0 + reg, dd[reg]);
            }
    }
}

// ---- fused single-kernel exclusive scan (196 blocks, all co-resident) ------
__global__ __launch_bounds__(256) void scan_fused_kernel(
        const int* __restrict__ deg, int* __restrict__ row_start,
        int* __restrict__ partials, int* __restrict__ pprefix,
        int* __restrict__ gcount, int* __restrict__ gflag, int N, int n,
        const float* __restrict__ mean_acc, float Einv,
        const float* __restrict__ we_vec1, const float* __restrict__ we_vec2,
        float* __restrict__ ae_loop) {
    __shared__ int s[256];
    __shared__ int amLast, bprefix;
    int t = threadIdx.x, bid = blockIdx.x;
    int i = bid * 256 + t;
    int v = (i < N) ? deg[i] : 0;
    s[t] = v; __syncthreads();
    for (int off = 1; off < 256; off <<= 1) {
        int u = (t >= off) ? s[t - off] : 0;
        __syncthreads();
        s[t] += u;
        __syncthreads();
    }
    int incl = s[t];
    int total = s[255];
    if (t == 0) {
        partials[bid] = total;
        __threadfence();
        int c = __hip_atomic_fetch_add(gcount, 1, __ATOMIC_ACQ_REL, __HIP_MEMORY_SCOPE_AGENT);
        amLast = (c == (int)gridDim.x - 1);
    }
    __syncthreads();
    if (amLast) {
        int G = gridDim.x;
        int pv = (t < G) ? ld_acq(&partials[t]) : 0;
        __syncthreads();           // s[] reuse
        s[t] = pv; __syncthreads();
        for (int off = 1; off < 256; off <<= 1) {
            int u = (t >= off) ? s[t - off] : 0;
            __syncthreads();
            s[t] += u;
            __syncthreads();
        }
        if (t < G) pprefix[t] = s[t] - pv;
        if (t == 0) {
            float s1 = 0.f, s2 = 0.f;
#pragma unroll
            for (int j = 0; j < 8; ++j) {
                float m = mean_acc[j] * Einv;
                s1 += m * we_vec1[j];
                s2 += m * we_vec2[j];
            }
            ae_loop[0] = s1; ae_loop[1] = s2;
        }
        __threadfence();
        __syncthreads();
        if (t == 0) st_rel(gflag, 1);
    }
    if (t == 0) {
        while (ld_acq(gflag) == 0) __builtin_amdgcn_s_sleep(2);
        bprefix = ld_acq(&pprefix[bid]);
    }
    __syncthreads();
    int ex = bprefix + incl - v;
    if (i < n) row_start[i] = ex;
}

// ---- CSR fill: atomic-free (slot = row_start[dst] + rank), max TLP ---------
__global__ __launch_bounds__(256) void fill_kernel(
        const int* __restrict__ src, const int* __restrict__ dst,
        const float2* __restrict__ aEe, const int* __restrict__ row_start,
        const int* __restrict__ rank,
        float4* __restrict__ epack, int E) {
    int e = blockIdx.x * 256 + threadIdx.x;
    if (e >= E) return;
    int d = dst[e];
    int idx = row_start[d] + rank[e];
    float2 a = aEe[e];
    epack[idx] = make_float4(__int_as_float(src[e]), a.x, a.y, 0.f);
}

// ---- gemm2: 128x128, A already bf16 ----------------------------------------
#define LDA2 40
__global__ __launch_bounds__(256) void gemm_mfma_kernel(
        const u16* __restrict__ A_g,
        const u16* __restrict__ Bh_g, const u16* __restrict__ Bl_g,
        u16* __restrict__ Cb, int Nrows, int K, int M,
        const float* __restrict__ av, const float* __restrict__ bv,
        float* __restrict__ as_out, float* __restrict__ ad_out) {
    __shared__ u16 Ah[128 * LDA2], Bh[128 * LDA2], Bl[128 * LDA2];
    int tid = threadIdx.x;
    int lane = tid & 63;
    int wv = tid >> 6;
    int wm = wv >> 1, wn = wv & 1;
    int l15 = lane & 15, quad = lane >> 4;
    int rb = blockIdx.y * 128;
    int cb = blockIdx.x * 128;

    v4f acc[4][4];
#pragma unroll
    for (int mi = 0; mi < 4; ++mi)
#pragma unroll
        for (int ni = 0; ni < 4; ++ni) acc[mi][ni] = (v4f){0.f, 0.f, 0.f, 0.f};

    int sr = tid >> 1;
    int sc = (tid & 1) * 16;

    for (int kc = 0; kc < K; kc += BK) {
        int gr = rb + sr;
        u16x8 a0 = {0,0,0,0,0,0,0,0}, a1 = {0,0,0,0,0,0,0,0};
        if (gr < Nrows) {
            size_t ba = (size_t)gr * K + kc + sc;
            a0 = *(const u16x8*)(A_g + ba);
            a1 = *(const u16x8*)(A_g + ba + 8);
        }
        size_t bb = (size_t)(cb + sr) * K + kc + sc;
        u16x8 b0 = *(const u16x8*)(Bh_g + bb);
        u16x8 b1 = *(const u16x8*)(Bh_g + bb + 8);
        u16x8 b2 = *(const u16x8*)(Bl_g + bb);
        u16x8 b3 = *(const u16x8*)(Bl_g + bb + 8);
        *(u16x8*)&Ah[sr * LDA2 + sc] = a0;
        *(u16x8*)&Ah[sr * LDA2 + sc + 8] = a1;
        *(u16x8*)&Bh[sr * LDA2 + sc] = b0;
        *(u16x8*)&Bh[sr * LDA2 + sc + 8] = b1;
        *(u16x8*)&Bl[sr * LDA2 + sc] = b2;
        *(u16x8*)&Bl[sr * LDA2 + sc + 8] = b3;
        __syncthreads();
        short8 ah[4], bh[4], bl[4];
#pragma unroll
        for (int mi = 0; mi < 4; ++mi)
            ah[mi] = *(const short8*)&Ah[(wm * 64 + mi * 16 + l15) * LDA2 + quad * 8];
#pragma unroll
        for (int ni = 0; ni < 4; ++ni) {
            int r = (wn * 64 + ni * 16 + l15) * LDA2 + quad * 8;
            bh[ni] = *(const short8*)&Bh[r];
            bl[ni] = *(const short8*)&Bl[r];
        }
#pragma unroll
        for (int mi = 0; mi < 4; ++mi)
#pragma unroll
            for (int ni = 0; ni < 4; ++ni) {
                acc[mi][ni] = __builtin_amdgcn_mfma_f32_16x16x32_bf16(ah[mi], bh[ni], acc[mi][ni], 0, 0, 0);
                acc[mi][ni] = __builtin_amdgcn_mfma_f32_16x16x32_bf16(ah[mi], bl[ni], acc[mi][ni], 0, 0, 0);
            }
        __syncthreads();
    }
#pragma unroll
    for (int mi = 0; mi < 4; ++mi)
#pragma unroll
        for (int ni = 0; ni < 4; ++ni)
#pragma unroll
            for (int reg = 0; reg < 4; ++reg) {
                int row = rb + wm * 64 + mi * 16 + quad * 4 + reg;
                if (row < Nrows)
                    Cb[(size_t)row * M + cb + wn * 64 + ni * 16 + l15] = f2bf(acc[mi][ni][reg]);
            }
    float sd[4][4] = {}, dd[4][4] = {};
#pragma unroll
    for (int ni = 0; ni < 4; ++ni) {
        int col = cb + wn * 64 + ni * 16 + l15;
        float a = av[col], b = bv[col];
#pragma unroll
        for (int mi = 0; mi < 4; ++mi)
#pragma unroll
            for (int reg = 0; reg < 4; ++reg) {
                sd[mi][reg] += acc[mi][ni][reg] * a;
                dd[mi][reg] += acc[mi][ni][reg] * b;
            }
    }
#pragma unroll
    for (int off = 1; off < 16; off <<= 1)
#pragma unroll
        for (int mi = 0; mi < 4; ++mi)
#pragma unroll
            for (int reg = 0; reg < 4; ++reg) {
                sd[mi][reg] += __shfl_xor(sd[mi][reg], off);
                dd[mi][reg] += __shfl_xor(dd[mi][reg], off);
            }
    if (l15 == 0)
#pragma unroll
        for (int mi = 0; mi < 4; ++mi) {
            int row0 = rb + wm * 64 + mi * 16 + quad * 4;
#pragma unroll
            for (int reg = 0; reg < 4; ++reg)
                if (row0 + reg < Nrows) {
                    atomicAdd(as_out + row0 + reg, sd[mi][reg]);
                    atomicAdd(ad_out + row0 + reg, dd[mi][reg]);
                }
        }
}

// ---- single-pass FLASH softmax-aggregation, L1 (C=256), wave per node ------
__global__ __launch_bounds__(256) void agg1_kernel(const int* __restrict__ row_start,
                                                   const float4* __restrict__ epack,
                                                   const float* __restrict__ asv,
                                                   const float* __restrict__ adv,
                                                   const float* __restrict__ ae_loop,
                                                   const u16* __restrict__ Hb,
                                                   u16* __restrict__ ohi,
                                                   const float* __restrict__ bias, int N) {
    __shared__ float2 xch[4][64];
    int lane = threadIdx.x & 63;
    int wvi = threadIdx.x >> 6;
    int node = blockIdx.x * 4 + wvi;
    if (node >= N) return;
    int st = row_start[node], en = row_start[node + 1];
    float ad = adv[node];
    float aloop = lrelu(asv[node] + ad + ae_loop[0]);
    float m = aloop, sum = 1.f;
    float acc0, acc1, acc2, acc3;
    {
        int2 hv = *(const int2*)(Hb + (size_t)node * 256 + lane * 4);
        acc0 = bf_lo(hv.x); acc1 = bf_hi(hv.x);
        acc2 = bf_lo(hv.y); acc3 = bf_hi(hv.y);
    }
    for (int base = st; base < en; base += 64) {
        int i = base + lane;
        float al = -3.0e38f; int sreg = 0;
        if (i < en) {
            float4 ep = epack[i];
            sreg = __float_as_int(ep.x);
            al = lrelu(asv[sreg] + ad + ep.y);
        }
        float cm = al;
#pragma unroll
        for (int o = 1; o < 64; o <<= 1) cm = fmaxf(cm, __shfl_xor(cm, o));
        if (cm > m) {
            float sc = __expf(m - cm);
            acc0 *= sc; acc1 *= sc; acc2 *= sc; acc3 *= sc;
            sum *= sc; m = cm;
        }
        float w = (i < en) ? __expf(al - m) : 0.f;
        float wsum = w;
#pragma unroll
        for (int o = 1; o < 64; o <<= 1) wsum += __shfl_xor(wsum, o);
        sum += wsum;
        xch[wvi][lane] = make_float2(w, __int_as_float(sreg));
        int cnt = min(64, en - base);
        int j = 0;
        for (; j + 8 <= cnt; j += 8) {
            float2 e[8]; int2 h[8];
#pragma unroll
            for (int q = 0; q < 8; ++q) e[q] = xch[wvi][j + q];
#pragma unroll
            for (int q = 0; q < 8; ++q)
                h[q] = *(const int2*)(Hb + (size_t)__float_as_int(e[q].y) * 256 + lane * 4);
#pragma unroll
            for (int q = 0; q < 8; ++q) {
                acc0 += e[q].x * bf_lo(h[q].x); acc1 += e[q].x * bf_hi(h[q].x);
                acc2 += e[q].x * bf_lo(h[q].y); acc3 += e[q].x * bf_hi(h[q].y);
            }
        }
        for (; j + 4 <= cnt; j += 4) {
            float2 e0 = xch[wvi][j], e1 = xch[wvi][j + 1];
            float2 e2 = xch[wvi][j + 2], e3 = xch[wvi][j + 3];
            int2 h0 = *(const int2*)(Hb + (size_t)__float_as_int(e0.y) * 256 + lane * 4);
            int2 h1 = *(const int2*)(Hb + (size_t)__float_as_int(e1.y) * 256 + lane * 4);
            int2 h2 = *(const int2*)(Hb + (size_t)__float_as_int(e2.y) * 256 + lane * 4);
            int2 h3 = *(const int2*)(Hb + (size_t)__float_as_int(e3.y) * 256 + lane * 4);
            acc0 += e0.x * bf_lo(h0.x) + e1.x * bf_lo(h1.x) + e2.x * bf_lo(h2.x) + e3.x * bf_lo(h3.x);
            acc1 += e0.x * bf_hi(h0.x) + e1.x * bf_hi(h1.x) + e2.x * bf_hi(h2.x) + e3.x * bf_hi(h3.x);
            acc2 += e0.x * bf_lo(h0.y) + e1.x * bf_lo(h1.y) + e2.x * bf_lo(h2.y) + e3.x * bf_lo(h3.y);
            acc3 += e0.x * bf_hi(h0.y) + e1.x * bf_hi(h1.y) + e2.x * bf_hi(h2.y) + e3.x * bf_hi(h3.y);
        }
        for (; j < cnt; ++j) {
            float2 e0 = xch[wvi][j];
            int2 h0 = *(const int2*)(Hb + (size_t)__float_as_int(e0.y) * 256 + lane * 4);
            acc0 += e0.x * bf_lo(h0.x); acc1 += e0.x * bf_hi(h0.x);
            acc2 += e0.x * bf_lo(h0.y); acc3 += e0.x * bf_hi(h0.y);
        }
    }
    float inv = 1.f / sum;
    const float4 bvv = *(const float4*)(bias + lane * 4);
    float t0 = acc0 * inv + bvv.x, t1 = acc1 * inv + bvv.y;
    float t2 = acc2 * inv + bvv.z, t3 = acc3 * inv + bvv.w;
    t0 = t0 > 0.f ? t0 : 0.f; t1 = t1 > 0.f ? t1 : 0.f;
    t2 = t2 > 0.f ? t2 : 0.f; t3 = t3 > 0.f ? t3 : 0.f;
    u16x4 h;
    h.x = f2bf(t0); h.y = f2bf(t1); h.z = f2bf(t2); h.w = f2bf(t3);
    *(u16x4*)(ohi + (size_t)node * 256 + lane * 4) = h;
}

// ---- single-pass FLASH softmax-aggregation, L2 (C=128) ---------------------
__global__ __launch_bounds__(256) void agg2_kernel(const int* __restrict__ row_start,
                                                   const float4* __restrict__ epack,
                                                   const float* __restrict__ asv,
                                                   const float* __restrict__ adv,
                                                   const float* __restrict__ ae_loop,
                                                   const u16* __restrict__ Hb,
                                                   float* __restrict__ out,
                                                   const float* __restrict__ bias, int N) {
    __shared__ float2 xch[4][64];
    int lane = threadIdx.x & 63;
    int wvi = threadIdx.x >> 6;
    int node = blockIdx.x * 4 + wvi;
    if (node >= N) return;
    int st = row_start[node], en = row_start[node + 1];
    float ad = adv[node];
    float aloop = lrelu(asv[node] + ad + ae_loop[1]);
    float m = aloop, sum = 1.f;
    float acc0, acc1;
    {
        int hv = *(const int*)(Hb + (size_t)node * 128 + lane * 2);
        acc0 = bf_lo(hv); acc1 = bf_hi(hv);
    }
    for (int base = st; base < en; base += 64) {
        int i = base + lane;
        float al = -3.0e38f; int sreg = 0;
        if (i < en) {
            float4 ep = epack[i];
            sreg = __float_as_int(ep.x);
            al = lrelu(asv[sreg] + ad + ep.z);
        }
        float cm = al;
#pragma unroll
        for (int o = 1; o < 64; o <<= 1) cm = fmaxf(cm, __shfl_xor(cm, o));
        if (cm > m) {
            float sc = __expf(m - cm);
            acc0 *= sc; acc1 *= sc;
            sum *= sc; m = cm;
        }
        float w = (i < en) ? __expf(al - m) : 0.f;
        float wsum = w;
#pragma unroll
        for (int o = 1; o < 64; o <<= 1) wsum += __shfl_xor(wsum, o);
        sum += wsum;
        xch[wvi][lane] = make_float2(w, __int_as_float(sreg));
        int cnt = min(64, en - base);
        int j = 0;
        for (; j + 8 <= cnt; j += 8) {
            float2 e[8]; int h[8];
#pragma unroll
            for (int q = 0; q < 8; ++q) e[q] = xch[wvi][j + q];
#pragma unroll
            for (int q = 0; q < 8; ++q)
                h[q] = *(const int*)(Hb + (size_t)__float_as_int(e[q].y) * 128 + lane * 2);
#pragma unroll
            for (int q = 0; q < 8; ++q) {
                acc0 += e[q].x * bf_lo(h[q]); acc1 += e[q].x * bf_hi(h[q]);
            }
        }
        for (; j + 4 <= cnt; j += 4) {
            float2 e0 = xch[wvi][j], e1 = xch[wvi][j + 1];
            float2 e2 = xch[wvi][j + 2], e3 = xch[wvi][j + 3];
            int h0 = *(const int*)(Hb + (size_t)__float_as_int(e0.y) * 128 + lane * 2);
            int h1 = *(const int*)(Hb + (size_t)__float_as_int(e1.y) * 128 + lane * 2);
            int h2 = *(const int*)(Hb + (size_t)__float_as_int(e2.y) * 128 + lane * 2);
            int h3 = *(const int*)(Hb + (size_t)__float_as_int(e3.y) * 128 + lane * 2);
            acc0 += e0.x * bf_lo(h0) + e1.x * bf_lo(h1) + e2.x * bf_lo(h2) + e3.x * bf_lo(h3);
            acc1 += e0.x * bf_hi(h0) + e1.x * bf_hi(h1) + e2.x * bf_hi(h2) + e3.x * bf_hi(h3);
        }
        for (; j < cnt; ++j) {
            float2 e0 = xch[wvi][j];
            int h0 = *(const int*)(Hb + (size_t)__float_as_int(e0.y) * 128 + lane * 2);
            acc0 += e0.x * bf_lo(h0); acc1 += e0.x * bf_hi(h0);
        }
    }
    float inv = 1.f / sum;
    size_t o = (size_t)node * 128 + lane * 2;
    out[o]     = acc0 * inv + bias[lane * 2];
    out[o + 1] = acc1 * inv + bias[lane * 2 + 1];
}

extern "C" void kernel_launch(void* const* d_in, const int* in_sizes, int n_in,
                              void* d_out, int out_size, void* d_ws, size_t ws_size,
                              hipStream_t stream) {
    const int Cin = 128, Ch = 256, Co = 128;
    const int N = in_sizes[0] / Cin;        // 50000
    const int E = in_sizes[1] / 2;          // 800000

    const float* x   = (const float*)d_in[0];
    const int*   src = (const int*)d_in[1];
    const int*   dst = src + E;
    const float* ea  = (const float*)d_in[2];
    const float* W1  = (const float*)d_in[3];
    const float* We1 = (const float*)d_in[4];
    const float* as1 = (const float*)d_in[5];
    const float* ad1 = (const float*)d_in[6];
    const float* ae1 = (const float*)d_in[7];
    const float* b1  = (const float*)d_in[8];
    const float* W2  = (const float*)d_in[9];
    const float* We2 = (const float*)d_in[10];
    const float* as2 = (const float*)d_in[11];
    const float* ad2 = (const float*)d_in[12];
    const float* ae2 = (const float*)d_in[13];
    const float* b2  = (const float*)d_in[14];
    float* out = (float*)d_out;

    // workspace layout (4-byte units)
    float* ws = (float*)d_ws;
    size_t off = 0;
    u16* h1b = (u16*)(ws + off); off += (size_t)N * Ch / 2;   // bf16 h (reused as h2b)
    u16* g1b = (u16*)(ws + off); off += (size_t)N * Ch / 2;   // agg1 output (gemm2 A)
    float4* epack = (float4*)(ws + off); off += (size_t)E * 4;  // packed CSR edges
    float2* aEe   = (float2*)(ws + off); off += (size_t)E * 2;  // edge-order a_e
    int* rank     = (int*)(ws + off); off += (size_t)E;         // per-edge rank
    int* row_start = (int*)(ws + off); off += (size_t)N + 1;
    int* partials  = (int*)(ws + off); off += 256;
    int* pprefix   = (int*)(ws + off); off += 256;
    u16* w1thi = (u16*)(ws + off); off += (size_t)Cin * Ch / 2;
    u16* w1tlo = (u16*)(ws + off); off += (size_t)Cin * Ch / 2;
    u16* w2thi = (u16*)(ws + off); off += (size_t)Ch * Co / 2;
    u16* w2tlo = (u16*)(ws + off); off += (size_t)Ch * Co / 2;
    // contiguous zero-region: deg | asv1 adv1 asv2 adv2 | misc | sync
    int*   deg  = (int*)(ws + off); off += (size_t)N + 1;
    float* asv1 = ws + off; off += (size_t)N;
    float* adv1 = ws + off; off += (size_t)N;
    float* asv2 = ws + off; off += (size_t)N;
    float* adv2 = ws + off; off += (size_t)N;
    float* misc = ws + off; off += 32;
    float* mean_acc = misc;
    float* we_vec1  = misc + 8;
    float* we_vec2  = misc + 16;
    float* ae_loop  = misc + 24;
    int* gcount = (int*)(ws + off); off += 1;
    int* gflag  = (int*)(ws + off); off += 1;

    const int n1 = N + 1;
    const int nscan = (n1 + 255) / 256;   // 196 blocks <= 256 CUs (co-resident)

    // one memset zeroes deg + 4 dot-buffers + misc + sync flags
    hipMemsetAsync(deg, 0, ((size_t)5 * N + 35) * sizeof(float), stream);

    // ---- prep: W splits (256 blocks) + we_vec (1 block) --------------------
    prep_kernel<<<257, 256, 0, stream>>>(
        W1, w1thi, w1tlo, W2, w2thi, w2tlo,
        We1, ae1, We2, ae2, we_vec1, we_vec2);

    // ---- FAT: hist (1024, grid-stride) 1:1-interleaved with gemm1 64x128 ---
    {
        int Fb = 1024;
        int gx = Ch / 128;                       // 2
        int Gg = gx * ((N + 63) / 64);           // 1564
        fat1_kernel<<<Fb + Gg, 256, 0, stream>>>(
            ea, dst, mean_acc, deg, rank, aEe, E, we_vec1, we_vec2, Fb, Gg,
            x, w1thi, w1tlo, h1b, N, Cin, Ch, as1, ad1, asv1, adv1, gx);
    }

    // ---- fused scan (+ae_loop) ---------------------------------------------
    scan_fused_kernel<<<nscan, 256, 0, stream>>>(
        deg, row_start, partials, pprefix, gcount, gflag, N, n1,
        mean_acc, 1.0f / (float)E, we_vec1, we_vec2, ae_loop);

    // ---- CSR fill: atomic-free ---------------------------------------------
    fill_kernel<<<(E + 255) / 256, 256, 0, stream>>>(src, dst, aEe, row_start,
                                                     rank, epack, E);

    agg1_kernel<<<(N + 3) / 4, 256, 0, stream>>>(row_start, epack, asv1, adv1, ae_loop,
                                                 h1b, g1b, b1, N);

    // ---- layer 2 ----------------------------------------------------------
    u16* h2b = h1b; // reuse (agg1 consumed h1b)
    {
        dim3 grid(Co / 128, (N + 127) / 128);
        gemm_mfma_kernel<<<grid, 256, 0, stream>>>(g1b, w2thi, w2tlo, h2b, N, Ch, Co,
                                                   as2, ad2, asv2, adv2);
    }
    agg2_kernel<<<(N + 3) / 4, 256, 0, stream>>>(row_start, epack, asv2, adv2, ae_loop,
                                                 h2b, out, b2, N);
}

// Round 7
// 342.146 us; speedup vs baseline: 1.2637x; 1.0225x over previous
//
#include <hip/hip_runtime.h>
#include <hip/hip_bf16.h>

// ---------------------------------------------------------------------------
// 2-layer GATConv (heads=1). N=50000, E=800000, Cin=128, Ch=256, Co=128, Ed=8.
// 8-dispatch pipeline:
//   memset | prep (W-split + we_vec) | FAT [hist+rank+aEe ⟂ gemm1(64x128),
//   block-interleaved] | fused-scan | fill (atomic-free, +w1 precompute) |
//   agg1 | gemm2 | agg2
// R7: aggregation restructured. (1) no-max softmax (inputs bounded -> exp
// cannot overflow; mathematically identical). (2) layer-1 edge weight
// exp(lrelu(as+ad+ae)) precomputed in fill -> agg1 is pure gather-FMA.
// (3) 2-edges-per-wave split gather: lanes 0-31 edge j (int4 = 8 channels/
// lane), lanes 32-63 edge j+1; one shfl_xor(32) merge at the end. Halves
// gather instructions, doubles outstanding bytes.
// ---------------------------------------------------------------------------

#define NEG_SLOPE 0.2f

typedef unsigned short u16;
typedef short short8 __attribute__((ext_vector_type(8)));
typedef float v4f __attribute__((ext_vector_type(4)));
typedef u16 u16x8 __attribute__((ext_vector_type(8)));

__device__ __forceinline__ u16 f2bf(float f) {
    unsigned u = __float_as_uint(f);
    return (u16)((u + 0x7fffu + ((u >> 16) & 1u)) >> 16);
}
__device__ __forceinline__ float bf2f(u16 h) {
    return __uint_as_float(((unsigned)h) << 16);
}
__device__ __forceinline__ float bf_lo(int v) { return __uint_as_float(((unsigned)v) << 16); }
__device__ __forceinline__ float bf_hi(int v) { return __uint_as_float(((unsigned)v) & 0xffff0000u); }
__device__ __forceinline__ float lrelu(float x) {
    return x >= 0.f ? x : NEG_SLOPE * x;
}
__device__ __forceinline__ int ld_acq(int* p) {
    return __hip_atomic_load(p, __ATOMIC_ACQUIRE, __HIP_MEMORY_SCOPE_AGENT);
}
__device__ __forceinline__ void st_rel(int* p, int v) {
    __hip_atomic_store(p, v, __ATOMIC_RELEASE, __HIP_MEMORY_SCOPE_AGENT);
}

// ---- prep: [blocks 0..256): W1^T / W2^T bf16 hi/lo splits
//            [block 256]: we_vec1/2 = We^T @ ae (computed once, published) ---
__global__ __launch_bounds__(256) void prep_kernel(
        const float* __restrict__ W1, u16* __restrict__ w1thi, u16* __restrict__ w1tlo,
        const float* __restrict__ W2, u16* __restrict__ w2thi, u16* __restrict__ w2tlo,
        const float* __restrict__ We1, const float* __restrict__ ae1v,
        const float* __restrict__ We2, const float* __restrict__ ae2v,
        float* __restrict__ we_vec1g, float* __restrict__ we_vec2g) {
    int tid = threadIdx.x;
    if (blockIdx.x < 256) {
        int t = blockIdx.x * 256 + tid;
        if (t < 128 * 256) {               // W1 [Cin=128][Ch=256]
            int k = t >> 8, m = t & 255;
            float v = W1[t];
            u16 h = f2bf(v);
            w1thi[(size_t)m * 128 + k] = h;
            w1tlo[(size_t)m * 128 + k] = f2bf(v - bf2f(h));
        } else {                           // W2 [Ch=256][Co=128]
            t -= 128 * 256;
            int k = t >> 7, m = t & 127;
            float v = W2[t];
            u16 h = f2bf(v);
            w2thi[(size_t)m * 256 + k] = h;
            w2tlo[(size_t)m * 256 + k] = f2bf(v - bf2f(h));
        }
        return;
    }
    // ---- we_vec: wv[j] = sum_k We1[j][k]*ae1v[k]; wv[8+j] for We2 ----
    __shared__ float wv[16];
    if (tid < 16) wv[tid] = 0.f;
    __syncthreads();
    {
        float a1 = ae1v[tid];              // Ch == 256 == blockDim
        int lane = tid & 63;
#pragma unroll
        for (int j = 0; j < 8; ++j) {
            float v = We1[j * 256 + tid] * a1;
#pragma unroll
            for (int o = 32; o; o >>= 1) v += __shfl_down(v, o);
            if (lane == 0) atomicAdd(&wv[j], v);
        }
        if (tid < 128) {
            float a2 = ae2v[tid];          // Co == 128
#pragma unroll
            for (int j = 0; j < 8; ++j) {
                float v = We2[j * 128 + tid] * a2;
#pragma unroll
                for (int o = 32; o; o >>= 1) v += __shfl_down(v, o);
                if (lane == 0) atomicAdd(&wv[8 + j], v);
            }
        }
    }
    __syncthreads();
    if (tid < 8)  we_vec1g[tid] = wv[tid];
    else if (tid < 16) we_vec2g[tid - 8] = wv[tid];
}

// ---- FAT: hist (grid-stride, Fb blocks) 1:1-interleaved with gemm1 64x128 --
#define BK 32
#define LDA 40   // 32 + 8 pad (u16)
__global__ __launch_bounds__(256) void fat1_kernel(
        // hist args
        const float* __restrict__ ea, const int* __restrict__ dst,
        float* __restrict__ mean_acc, int* __restrict__ deg,
        int* __restrict__ rank, float2* __restrict__ aEe, int E,
        const float* __restrict__ we_vec1g, const float* __restrict__ we_vec2g,
        int Fb, int Gg,
        // gemm args (64 rows x 128 cols tile)
        const float* __restrict__ A32,
        const u16* __restrict__ Bh_g, const u16* __restrict__ Bl_g,
        u16* __restrict__ Cb, int Nrows, int K, int M,
        const float* __restrict__ av, const float* __restrict__ bv,
        float* __restrict__ as_out, float* __restrict__ ad_out, int gx) {
    __shared__ u16 Ah[64 * LDA];          // 5.1 KB
    __shared__ u16 Bh[128 * LDA];         // 10.2 KB
    __shared__ u16 Bl[128 * LDA];         // 10.2 KB  -> 25.6 KB total
    __shared__ float red[8];
    int tid = threadIdx.x;
    int bid = (int)blockIdx.x;
    int mn = Fb < Gg ? Fb : Gg;
    int hid = -1, gid = -1;
    if (bid < 2 * mn) {
        if ((bid & 1) == 0) hid = bid >> 1; else gid = bid >> 1;
    } else {
        int rem = bid - 2 * mn;
        if (Fb > Gg) hid = mn + rem; else gid = mn + rem;
    }
    if (hid >= 0) {
        // ---- hist branch: grid-stride edges, returning fetch-add ----
        float wv[16];
#pragma unroll
        for (int j = 0; j < 8; ++j) { wv[j] = we_vec1g[j]; wv[8 + j] = we_vec2g[j]; }
        if (tid < 8) red[tid] = 0.f;
        __syncthreads();
        float s[8] = {0.f};
        int stride = Fb * 256;
        for (int e = hid * 256 + tid; e < E; e += stride) {
            int d = dst[e];
            const float4 v0 = *(const float4*)&ea[(size_t)e * 8];
            const float4 v1 = *(const float4*)&ea[(size_t)e * 8 + 4];
            s[0] += v0.x; s[1] += v0.y; s[2] += v0.z; s[3] += v0.w;
            s[4] += v1.x; s[5] += v1.y; s[6] += v1.z; s[7] += v1.w;
            float s1 = v0.x * wv[0] + v0.y * wv[1] + v0.z * wv[2] + v0.w * wv[3]
                     + v1.x * wv[4] + v1.y * wv[5] + v1.z * wv[6] + v1.w * wv[7];
            float s2 = v0.x * wv[8] + v0.y * wv[9] + v0.z * wv[10] + v0.w * wv[11]
                     + v1.x * wv[12] + v1.y * wv[13] + v1.z * wv[14] + v1.w * wv[15];
            aEe[e] = make_float2(s1, s2);
            rank[e] = atomicAdd(&deg[d], 1);   // arrival rank
        }
        int lane = tid & 63;
#pragma unroll
        for (int j = 0; j < 8; ++j) {
#pragma unroll
            for (int o = 32; o; o >>= 1) s[j] += __shfl_down(s[j], o);
            if (lane == 0) atomicAdd(&red[j], s[j]);
        }
        __syncthreads();
        if (tid < 8) atomicAdd(&mean_acc[tid], red[tid]);
        return;
    }
    // ---- gemm1 branch: 64x128 tile, 4 waves, each wave 16 rows x 128 cols --
    int lane = tid & 63;
    int wvx = tid >> 6;
    int l15 = lane & 15, quad = lane >> 4;
    int rb = (gid / gx) * 64;
    int cb = (gid % gx) * 128;

    v4f acc[8];
#pragma unroll
    for (int ni = 0; ni < 8; ++ni) acc[ni] = (v4f){0.f, 0.f, 0.f, 0.f};

    int sr  = tid >> 2;            // 0..63  (A rows)
    int sc  = (tid & 3) * 8;       // 0,8,16,24
    int sr2 = tid >> 1;            // 0..127 (B rows)
    int sc2 = (tid & 1) * 16;      // 0,16

    for (int kc = 0; kc < K; kc += BK) {
        int gr = rb + sr;
        u16x8 a0 = {0,0,0,0,0,0,0,0};
        if (gr < Nrows) {
            const float* pa = A32 + (size_t)gr * K + kc + sc;
            float4 f0 = *(const float4*)pa;
            float4 f1 = *(const float4*)(pa + 4);
            a0 = (u16x8){f2bf(f0.x), f2bf(f0.y), f2bf(f0.z), f2bf(f0.w),
                         f2bf(f1.x), f2bf(f1.y), f2bf(f1.z), f2bf(f1.w)};
        }
        size_t bb = (size_t)(cb + sr2) * K + kc + sc2;
        u16x8 b0 = *(const u16x8*)(Bh_g + bb);
        u16x8 b1 = *(const u16x8*)(Bh_g + bb + 8);
        u16x8 b2 = *(const u16x8*)(Bl_g + bb);
        u16x8 b3 = *(const u16x8*)(Bl_g + bb + 8);
        *(u16x8*)&Ah[sr * LDA + sc] = a0;
        *(u16x8*)&Bh[sr2 * LDA + sc2] = b0;
        *(u16x8*)&Bh[sr2 * LDA + sc2 + 8] = b1;
        *(u16x8*)&Bl[sr2 * LDA + sc2] = b2;
        *(u16x8*)&Bl[sr2 * LDA + sc2 + 8] = b3;
        __syncthreads();
        short8 ah = *(const short8*)&Ah[(wvx * 16 + l15) * LDA + quad * 8];
#pragma unroll
        for (int ni = 0; ni < 8; ++ni) {
            int r = (ni * 16 + l15) * LDA + quad * 8;
            short8 bhf = *(const short8*)&Bh[r];
            short8 blf = *(const short8*)&Bl[r];
            acc[ni] = __builtin_amdgcn_mfma_f32_16x16x32_bf16(ah, bhf, acc[ni], 0, 0, 0);
            acc[ni] = __builtin_amdgcn_mfma_f32_16x16x32_bf16(ah, blf, acc[ni], 0, 0, 0);
        }
        __syncthreads();
    }
#pragma unroll
    for (int ni = 0; ni < 8; ++ni)
#pragma unroll
        for (int reg = 0; reg < 4; ++reg) {
            int row = rb + wvx * 16 + quad * 4 + reg;
            if (row < Nrows)
                Cb[(size_t)row * M + cb + ni * 16 + l15] = f2bf(acc[ni][reg]);
        }
    float sd[4] = {}, dd[4] = {};
#pragma unroll
    for (int ni = 0; ni < 8; ++ni) {
        int col = cb + ni * 16 + l15;
        float a = av[col], b = bv[col];
#pragma unroll
        for (int reg = 0; reg < 4; ++reg) {
            sd[reg] += acc[ni][reg] * a;
            dd[reg] += acc[ni][reg] * b;
        }
    }
#pragma unroll
    for (int off = 1; off < 16; off <<= 1)
#pragma unroll
        for (int reg = 0; reg < 4; ++reg) {
            sd[reg] += __shfl_xor(sd[reg], off);
            dd[reg] += __shfl_xor(dd[reg], off);
        }
    if (l15 == 0) {
        int row0 = rb + wvx * 16 + quad * 4;
#pragma unroll
        for (int reg = 0; reg < 4; ++reg)
            if (row0 + reg < Nrows) {
                atomicAdd(as_out + row0 + reg, sd[reg]);
                atomicAdd(ad_out + row0 + reg, dd[reg]);
            }
    }
}

// ---- fused single-kernel exclusive scan (196 blocks, all co-resident) ------
__global__ __launch_bounds__(256) void scan_fused_kernel(
        const int* __restrict__ deg, int* __restrict__ row_start,
        int* __restrict__ partials, int* __restrict__ pprefix,
        int* __restrict__ gcount, int* __restrict__ gflag, int N, int n,
        const float* __restrict__ mean_acc, float Einv,
        const float* __restrict__ we_vec1, const float* __restrict__ we_vec2,
        float* __restrict__ ae_loop) {
    __shared__ int s[256];
    __shared__ int amLast, bprefix;
    int t = threadIdx.x, bid = blockIdx.x;
    int i = bid * 256 + t;
    int v = (i < N) ? deg[i] : 0;
    s[t] = v; __syncthreads();
    for (int off = 1; off < 256; off <<= 1) {
        int u = (t >= off) ? s[t - off] : 0;
        __syncthreads();
        s[t] += u;
        __syncthreads();
    }
    int incl = s[t];
    int total = s[255];
    if (t == 0) {
        partials[bid] = total;
        __threadfence();
        int c = __hip_atomic_fetch_add(gcount, 1, __ATOMIC_ACQ_REL, __HIP_MEMORY_SCOPE_AGENT);
        amLast = (c == (int)gridDim.x - 1);
    }
    __syncthreads();
    if (amLast) {
        int G = gridDim.x;
        int pv = (t < G) ? ld_acq(&partials[t]) : 0;
        __syncthreads();           // s[] reuse
        s[t] = pv; __syncthreads();
        for (int off = 1; off < 256; off <<= 1) {
            int u = (t >= off) ? s[t - off] : 0;
            __syncthreads();
            s[t] += u;
            __syncthreads();
        }
        if (t < G) pprefix[t] = s[t] - pv;
        if (t == 0) {
            float s1 = 0.f, s2 = 0.f;
#pragma unroll
            for (int j = 0; j < 8; ++j) {
                float m = mean_acc[j] * Einv;
                s1 += m * we_vec1[j];
                s2 += m * we_vec2[j];
            }
            ae_loop[0] = s1; ae_loop[1] = s2;
        }
        __threadfence();
        __syncthreads();
        if (t == 0) st_rel(gflag, 1);
    }
    if (t == 0) {
        while (ld_acq(gflag) == 0) __builtin_amdgcn_s_sleep(2);
        bprefix = ld_acq(&pprefix[bid]);
    }
    __syncthreads();
    int ex = bprefix + incl - v;
    if (i < n) row_start[i] = ex;
}

// ---- CSR fill: atomic-free + layer-1 weight precompute ---------------------
// epack = (src, w1 = exp(lrelu(asv1[s]+adv1[d]+aEe.x)), aEe.y, 0)
__global__ __launch_bounds__(256) void fill_kernel(
        const int* __restrict__ src, const int* __restrict__ dst,
        const float2* __restrict__ aEe, const int* __restrict__ row_start,
        const int* __restrict__ rank,
        const float* __restrict__ asv1, const float* __restrict__ adv1,
        float4* __restrict__ epack, int E) {
    int e = blockIdx.x * 256 + threadIdx.x;
    if (e >= E) return;
    int d = dst[e];
    int s = src[e];
    int idx = row_start[d] + rank[e];
    float2 a = aEe[e];
    float w = __expf(lrelu(asv1[s] + adv1[d] + a.x));
    epack[idx] = make_float4(__int_as_float(s), w, a.y, 0.f);
}

// ---- gemm2: 128x128, A already bf16 ----------------------------------------
#define LDA2 40
__global__ __launch_bounds__(256) void gemm_mfma_kernel(
        const u16* __restrict__ A_g,
        const u16* __restrict__ Bh_g, const u16* __restrict__ Bl_g,
        u16* __restrict__ Cb, int Nrows, int K, int M,
        const float* __restrict__ av, const float* __restrict__ bv,
        float* __restrict__ as_out, float* __restrict__ ad_out) {
    __shared__ u16 Ah[128 * LDA2], Bh[128 * LDA2], Bl[128 * LDA2];
    int tid = threadIdx.x;
    int lane = tid & 63;
    int wv = tid >> 6;
    int wm = wv >> 1, wn = wv & 1;
    int l15 = lane & 15, quad = lane >> 4;
    int rb = blockIdx.y * 128;
    int cb = blockIdx.x * 128;

    v4f acc[4][4];
#pragma unroll
    for (int mi = 0; mi < 4; ++mi)
#pragma unroll
        for (int ni = 0; ni < 4; ++ni) acc[mi][ni] = (v4f){0.f, 0.f, 0.f, 0.f};

    int sr = tid >> 1;
    int sc = (tid & 1) * 16;

    for (int kc = 0; kc < K; kc += BK) {
        int gr = rb + sr;
        u16x8 a0 = {0,0,0,0,0,0,0,0}, a1 = {0,0,0,0,0,0,0,0};
        if (gr < Nrows) {
            size_t ba = (size_t)gr * K + kc + sc;
            a0 = *(const u16x8*)(A_g + ba);
            a1 = *(const u16x8*)(A_g + ba + 8);
        }
        size_t bb = (size_t)(cb + sr) * K + kc + sc;
        u16x8 b0 = *(const u16x8*)(Bh_g + bb);
        u16x8 b1 = *(const u16x8*)(Bh_g + bb + 8);
        u16x8 b2 = *(const u16x8*)(Bl_g + bb);
        u16x8 b3 = *(const u16x8*)(Bl_g + bb + 8);
        *(u16x8*)&Ah[sr * LDA2 + sc] = a0;
        *(u16x8*)&Ah[sr * LDA2 + sc + 8] = a1;
        *(u16x8*)&Bh[sr * LDA2 + sc] = b0;
        *(u16x8*)&Bh[sr * LDA2 + sc + 8] = b1;
        *(u16x8*)&Bl[sr * LDA2 + sc] = b2;
        *(u16x8*)&Bl[sr * LDA2 + sc + 8] = b3;
        __syncthreads();
        short8 ah[4], bh[4], bl[4];
#pragma unroll
        for (int mi = 0; mi < 4; ++mi)
            ah[mi] = *(const short8*)&Ah[(wm * 64 + mi * 16 + l15) * LDA2 + quad * 8];
#pragma unroll
        for (int ni = 0; ni < 4; ++ni) {
            int r = (wn * 64 + ni * 16 + l15) * LDA2 + quad * 8;
            bh[ni] = *(const short8*)&Bh[r];
            bl[ni] = *(const short8*)&Bl[r];
        }
#pragma unroll
        for (int mi = 0; mi < 4; ++mi)
#pragma unroll
            for (int ni = 0; ni < 4; ++ni) {
                acc[mi][ni] = __builtin_amdgcn_mfma_f32_16x16x32_bf16(ah[mi], bh[ni], acc[mi][ni], 0, 0, 0);
                acc[mi][ni] = __builtin_amdgcn_mfma_f32_16x16x32_bf16(ah[mi], bl[ni], acc[mi][ni], 0, 0, 0);
            }
        __syncthreads();
    }
#pragma unroll
    for (int mi = 0; mi < 4; ++mi)
#pragma unroll
        for (int ni = 0; ni < 4; ++ni)
#pragma unroll
            for (int reg = 0; reg < 4; ++reg) {
                int row = rb + wm * 64 + mi * 16 + quad * 4 + reg;
                if (row < Nrows)
                    Cb[(size_t)row * M + cb + wn * 64 + ni * 16 + l15] = f2bf(acc[mi][ni][reg]);
            }
    float sd[4][4] = {}, dd[4][4] = {};
#pragma unroll
    for (int ni = 0; ni < 4; ++ni) {
        int col = cb + wn * 64 + ni * 16 + l15;
        float a = av[col], b = bv[col];
#pragma unroll
        for (int mi = 0; mi < 4; ++mi)
#pragma unroll
            for (int reg = 0; reg < 4; ++reg) {
                sd[mi][reg] += acc[mi][ni][reg] * a;
                dd[mi][reg] += acc[mi][ni][reg] * b;
            }
    }
#pragma unroll
    for (int off = 1; off < 16; off <<= 1)
#pragma unroll
        for (int mi = 0; mi < 4; ++mi)
#pragma unroll
            for (int reg = 0; reg < 4; ++reg) {
                sd[mi][reg] += __shfl_xor(sd[mi][reg], off);
                dd[mi][reg] += __shfl_xor(dd[mi][reg], off);
            }
    if (l15 == 0)
#pragma unroll
        for (int mi = 0; mi < 4; ++mi) {
            int row0 = rb + wm * 64 + mi * 16 + quad * 4;
#pragma unroll
            for (int reg = 0; reg < 4; ++reg)
                if (row0 + reg < Nrows) {
                    atomicAdd(as_out + row0 + reg, sd[mi][reg]);
                    atomicAdd(ad_out + row0 + reg, dd[mi][reg]);
                }
        }
}

// ---- agg1: no-max softmax, precomputed w, 2-edges/wave split gather --------
// lanes 0-31: edge j, channels hl*8..hl*8+7 (int4); lanes 32-63: edge j+1.
__global__ __launch_bounds__(256) void agg1_kernel(const int* __restrict__ row_start,
                                                   const float4* __restrict__ epack,
                                                   const float* __restrict__ asv,
                                                   const float* __restrict__ adv,
                                                   const float* __restrict__ ae_loop,
                                                   const u16* __restrict__ Hb,
                                                   u16* __restrict__ ohi,
                                                   const float* __restrict__ bias, int N) {
    __shared__ float2 xch[4][64];
    int lane = threadIdx.x & 63;
    int wvi = threadIdx.x >> 6;
    int node = blockIdx.x * 4 + wvi;
    if (node >= N) return;
    int st = row_start[node], en = row_start[node + 1];
    float wloop = __expf(lrelu(asv[node] + adv[node] + ae_loop[0]));
    float sum = wloop;
    int half = lane >> 5;     // 0 or 1
    int hl   = lane & 31;     // 0..31
    float acc[8];
    {
        int4 hv = *(const int4*)(Hb + (size_t)node * 256 + hl * 8);
        float w0 = half ? 0.f : wloop;
        acc[0] = w0 * bf_lo(hv.x); acc[1] = w0 * bf_hi(hv.x);
        acc[2] = w0 * bf_lo(hv.y); acc[3] = w0 * bf_hi(hv.y);
        acc[4] = w0 * bf_lo(hv.z); acc[5] = w0 * bf_hi(hv.z);
        acc[6] = w0 * bf_lo(hv.w); acc[7] = w0 * bf_hi(hv.w);
    }
    for (int base = st; base < en; base += 64) {
        int i = base + lane;
        float w = 0.f; int sreg = 0;
        if (i < en) {
            float4 ep = epack[i];
            sreg = __float_as_int(ep.x);
            w = ep.y;                       // precomputed exp weight
        }
        float wsum = w;
#pragma unroll
        for (int o = 1; o < 64; o <<= 1) wsum += __shfl_xor(wsum, o);
        sum += wsum;
        xch[wvi][lane] = make_float2(w, __int_as_float(sreg));
        int cnt = min(64, en - base);
        int j = 0;
        for (; j + 8 <= cnt; j += 8) {     // 8 edges = 4 pair-iterations
            float2 e[4]; int4 h[4];
#pragma unroll
            for (int q = 0; q < 4; ++q) e[q] = xch[wvi][j + 2 * q + half];
#pragma unroll
            for (int q = 0; q < 4; ++q)
                h[q] = *(const int4*)(Hb + (size_t)__float_as_int(e[q].y) * 256 + hl * 8);
#pragma unroll
            for (int q = 0; q < 4; ++q) {
                float w0 = e[q].x;
                acc[0] += w0 * bf_lo(h[q].x); acc[1] += w0 * bf_hi(h[q].x);
                acc[2] += w0 * bf_lo(h[q].y); acc[3] += w0 * bf_hi(h[q].y);
                acc[4] += w0 * bf_lo(h[q].z); acc[5] += w0 * bf_hi(h[q].z);
                acc[6] += w0 * bf_lo(h[q].w); acc[7] += w0 * bf_hi(h[q].w);
            }
        }
        for (; j + 2 <= cnt; j += 2) {
            float2 e0 = xch[wvi][j + half];
            int4 h0 = *(const int4*)(Hb + (size_t)__float_as_int(e0.y) * 256 + hl * 8);
            float w0 = e0.x;
            acc[0] += w0 * bf_lo(h0.x); acc[1] += w0 * bf_hi(h0.x);
            acc[2] += w0 * bf_lo(h0.y); acc[3] += w0 * bf_hi(h0.y);
            acc[4] += w0 * bf_lo(h0.z); acc[5] += w0 * bf_hi(h0.z);
            acc[6] += w0 * bf_lo(h0.w); acc[7] += w0 * bf_hi(h0.w);
        }
        if (j < cnt && half == 0) {        // odd remainder: half 0 only
            float2 e0 = xch[wvi][j];
            int4 h0 = *(const int4*)(Hb + (size_t)__float_as_int(e0.y) * 256 + hl * 8);
            float w0 = e0.x;
            acc[0] += w0 * bf_lo(h0.x); acc[1] += w0 * bf_hi(h0.x);
            acc[2] += w0 * bf_lo(h0.y); acc[3] += w0 * bf_hi(h0.y);
            acc[4] += w0 * bf_lo(h0.z); acc[5] += w0 * bf_hi(h0.z);
            acc[6] += w0 * bf_lo(h0.w); acc[7] += w0 * bf_hi(h0.w);
        }
    }
#pragma unroll
    for (int c = 0; c < 8; ++c) acc[c] += __shfl_xor(acc[c], 32);
    if (half == 0) {
        float inv = 1.f / sum;
        const float4 b0 = *(const float4*)(bias + hl * 8);
        const float4 b1 = *(const float4*)(bias + hl * 8 + 4);
        float t0 = acc[0] * inv + b0.x, t1 = acc[1] * inv + b0.y;
        float t2 = acc[2] * inv + b0.z, t3 = acc[3] * inv + b0.w;
        float t4 = acc[4] * inv + b1.x, t5 = acc[5] * inv + b1.y;
        float t6 = acc[6] * inv + b1.z, t7 = acc[7] * inv + b1.w;
        t0 = t0 > 0.f ? t0 : 0.f; t1 = t1 > 0.f ? t1 : 0.f;
        t2 = t2 > 0.f ? t2 : 0.f; t3 = t3 > 0.f ? t3 : 0.f;
        t4 = t4 > 0.f ? t4 : 0.f; t5 = t5 > 0.f ? t5 : 0.f;
        t6 = t6 > 0.f ? t6 : 0.f; t7 = t7 > 0.f ? t7 : 0.f;
        u16x8 h;
        h[0] = f2bf(t0); h[1] = f2bf(t1); h[2] = f2bf(t2); h[3] = f2bf(t3);
        h[4] = f2bf(t4); h[5] = f2bf(t5); h[6] = f2bf(t6); h[7] = f2bf(t7);
        *(u16x8*)(ohi + (size_t)node * 256 + hl * 8) = h;
    }
}

// ---- agg2: no-max softmax, in-kernel w, 2-edges/wave split gather ----------
// lanes 0-31: edge j, channels hl*4..hl*4+3 (int2); lanes 32-63: edge j+1.
__global__ __launch_bounds__(256) void agg2_kernel(const int* __restrict__ row_start,
                                                   const float4* __restrict__ epack,
                                                   const float* __restrict__ asv,
                                                   const float* __restrict__ adv,
                                                   const float* __restrict__ ae_loop,
                                                   const u16* __restrict__ Hb,
                                                   float* __restrict__ out,
                                                   const float* __restrict__ bias, int N) {
    __shared__ float2 xch[4][64];
    int lane = threadIdx.x & 63;
    int wvi = threadIdx.x >> 6;
    int node = blockIdx.x * 4 + wvi;
    if (node >= N) return;
    int st = row_start[node], en = row_start[node + 1];
    float ad = adv[node];
    float wloop = __expf(lrelu(asv[node] + ad + ae_loop[1]));
    float sum = wloop;
    int half = lane >> 5;
    int hl   = lane & 31;
    float acc[4];
    {
        int2 hv = *(const int2*)(Hb + (size_t)node * 128 + hl * 4);
        float w0 = half ? 0.f : wloop;
        acc[0] = w0 * bf_lo(hv.x); acc[1] = w0 * bf_hi(hv.x);
        acc[2] = w0 * bf_lo(hv.y); acc[3] = w0 * bf_hi(hv.y);
    }
    for (int base = st; base < en; base += 64) {
        int i = base + lane;
        float w = 0.f; int sreg = 0;
        if (i < en) {
            float4 ep = epack[i];
            sreg = __float_as_int(ep.x);
            w = __expf(lrelu(asv[sreg] + ad + ep.z));
        }
        float wsum = w;
#pragma unroll
        for (int o = 1; o < 64; o <<= 1) wsum += __shfl_xor(wsum, o);
        sum += wsum;
        xch[wvi][lane] = make_float2(w, __int_as_float(sreg));
        int cnt = min(64, en - base);
        int j = 0;
        for (; j + 8 <= cnt; j += 8) {
            float2 e[4]; int2 h[4];
#pragma unroll
            for (int q = 0; q < 4; ++q) e[q] = xch[wvi][j + 2 * q + half];
#pragma unroll
            for (int q = 0; q < 4; ++q)
                h[q] = *(const int2*)(Hb + (size_t)__float_as_int(e[q].y) * 128 + hl * 4);
#pragma unroll
            for (int q = 0; q < 4; ++q) {
                float w0 = e[q].x;
                acc[0] += w0 * bf_lo(h[q].x); acc[1] += w0 * bf_hi(h[q].x);
                acc[2] += w0 * bf_lo(h[q].y); acc[3] += w0 * bf_hi(h[q].y);
            }
        }
        for (; j + 2 <= cnt; j += 2) {
            float2 e0 = xch[wvi][j + half];
            int2 h0 = *(const int2*)(Hb + (size_t)__float_as_int(e0.y) * 128 + hl * 4);
            float w0 = e0.x;
            acc[0] += w0 * bf_lo(h0.x); acc[1] += w0 * bf_hi(h0.x);
            acc[2] += w0 * bf_lo(h0.y); acc[3] += w0 * bf_hi(h0.y);
        }
        if (j < cnt && half == 0) {
            float2 e0 = xch[wvi][j];
            int2 h0 = *(const int2*)(Hb + (size_t)__float_as_int(e0.y) * 128 + hl * 4);
            float w0 = e0.x;
            acc[0] += w0 * bf_lo(h0.x); acc[1] += w0 * bf_hi(h0.x);
            acc[2] += w0 * bf_lo(h0.y); acc[3] += w0 * bf_hi(h0.y);
        }
    }
#pragma unroll
    for (int c = 0; c < 4; ++c) acc[c] += __shfl_xor(acc[c], 32);
    if (half == 0) {
        float inv = 1.f / sum;
        const float4 bv = *(const float4*)(bias + hl * 4);
        float4 o;
        o.x = acc[0] * inv + bv.x;
        o.y = acc[1] * inv + bv.y;
        o.z = acc[2] * inv + bv.z;
        o.w = acc[3] * inv + bv.w;
        *(float4*)(out + (size_t)node * 128 + hl * 4) = o;
    }
}

extern "C" void kernel_launch(void* const* d_in, const int* in_sizes, int n_in,
                              void* d_out, int out_size, void* d_ws, size_t ws_size,
                              hipStream_t stream) {
    const int Cin = 128, Ch = 256, Co = 128;
    const int N = in_sizes[0] / Cin;        // 50000
    const int E = in_sizes[1] / 2;          // 800000

    const float* x   = (const float*)d_in[0];
    const int*   src = (const int*)d_in[1];
    const int*   dst = src + E;
    const float* ea  = (const float*)d_in[2];
    const float* W1  = (const float*)d_in[3];
    const float* We1 = (const float*)d_in[4];
    const float* as1 = (const float*)d_in[5];
    const float* ad1 = (const float*)d_in[6];
    const float* ae1 = (const float*)d_in[7];
    const float* b1  = (const float*)d_in[8];
    const float* W2  = (const float*)d_in[9];
    const float* We2 = (const float*)d_in[10];
    const float* as2 = (const float*)d_in[11];
    const float* ad2 = (const float*)d_in[12];
    const float* ae2 = (const float*)d_in[13];
    const float* b2  = (const float*)d_in[14];
    float* out = (float*)d_out;

    // workspace layout (4-byte units)
    float* ws = (float*)d_ws;
    size_t off = 0;
    u16* h1b = (u16*)(ws + off); off += (size_t)N * Ch / 2;   // bf16 h (reused as h2b)
    u16* g1b = (u16*)(ws + off); off += (size_t)N * Ch / 2;   // agg1 output (gemm2 A)
    float4* epack = (float4*)(ws + off); off += (size_t)E * 4;  // packed CSR edges
    float2* aEe   = (float2*)(ws + off); off += (size_t)E * 2;  // edge-order a_e
    int* rank     = (int*)(ws + off); off += (size_t)E;         // per-edge rank
    int* row_start = (int*)(ws + off); off += (size_t)N + 1;
    int* partials  = (int*)(ws + off); off += 256;
    int* pprefix   = (int*)(ws + off); off += 256;
    u16* w1thi = (u16*)(ws + off); off += (size_t)Cin * Ch / 2;
    u16* w1tlo = (u16*)(ws + off); off += (size_t)Cin * Ch / 2;
    u16* w2thi = (u16*)(ws + off); off += (size_t)Ch * Co / 2;
    u16* w2tlo = (u16*)(ws + off); off += (size_t)Ch * Co / 2;
    // contiguous zero-region: deg | asv1 adv1 asv2 adv2 | misc | sync
    int*   deg  = (int*)(ws + off); off += (size_t)N + 1;
    float* asv1 = ws + off; off += (size_t)N;
    float* adv1 = ws + off; off += (size_t)N;
    float* asv2 = ws + off; off += (size_t)N;
    float* adv2 = ws + off; off += (size_t)N;
    float* misc = ws + off; off += 32;
    float* mean_acc = misc;
    float* we_vec1  = misc + 8;
    float* we_vec2  = misc + 16;
    float* ae_loop  = misc + 24;
    int* gcount = (int*)(ws + off); off += 1;
    int* gflag  = (int*)(ws + off); off += 1;

    const int n1 = N + 1;
    const int nscan = (n1 + 255) / 256;   // 196 blocks <= 256 CUs (co-resident)

    // one memset zeroes deg + 4 dot-buffers + misc + sync flags
    hipMemsetAsync(deg, 0, ((size_t)5 * N + 35) * sizeof(float), stream);

    // ---- prep: W splits (256 blocks) + we_vec (1 block) --------------------
    prep_kernel<<<257, 256, 0, stream>>>(
        W1, w1thi, w1tlo, W2, w2thi, w2tlo,
        We1, ae1, We2, ae2, we_vec1, we_vec2);

    // ---- FAT: hist (1024, grid-stride) 1:1-interleaved with gemm1 64x128 ---
    {
        int Fb = 1024;
        int gx = Ch / 128;                       // 2
        int Gg = gx * ((N + 63) / 64);           // 1564
        fat1_kernel<<<Fb + Gg, 256, 0, stream>>>(
            ea, dst, mean_acc, deg, rank, aEe, E, we_vec1, we_vec2, Fb, Gg,
            x, w1thi, w1tlo, h1b, N, Cin, Ch, as1, ad1, asv1, adv1, gx);
    }

    // ---- fused scan (+ae_loop) ---------------------------------------------
    scan_fused_kernel<<<nscan, 256, 0, stream>>>(
        deg, row_start, partials, pprefix, gcount, gflag, N, n1,
        mean_acc, 1.0f / (float)E, we_vec1, we_vec2, ae_loop);

    // ---- CSR fill: atomic-free, precompute layer-1 edge weights ------------
    fill_kernel<<<(E + 255) / 256, 256, 0, stream>>>(src, dst, aEe, row_start,
                                                     rank, asv1, adv1, epack, E);

    agg1_kernel<<<(N + 3) / 4, 256, 0, stream>>>(row_start, epack, asv1, adv1, ae_loop,
                                                 h1b, g1b, b1, N);

    // ---- layer 2 ----------------------------------------------------------
    u16* h2b = h1b; // reuse (agg1 consumed h1b)
    {
        dim3 grid(Co / 128, (N + 127) / 128);
        gemm_mfma_kernel<<<grid, 256, 0, stream>>>(g1b, w2thi, w2tlo, h2b, N, Ch, Co,
                                                   as2, ad2, asv2, adv2);
    }
    agg2_kernel<<<(N + 3) / 4, 256, 0, stream>>>(row_start, epack, asv2, adv2, ae_loop,
                                                 h2b, out, b2, N);
}